// Round 1
// baseline (828.871 us; speedup 1.0000x reference)
//
#include <hip/hip_runtime.h>

#define N_NODES 50000
#define N_EDGES 400000
#define IN_CH 32
#define M_CH 64
#define EPS 1e-5f

// ---------------- CSR build ----------------
__global__ void hist_kernel(const int* __restrict__ ei, int* __restrict__ cnt) {
    int e = blockIdx.x * 256 + threadIdx.x;
    if (e < N_EDGES) atomicAdd(&cnt[ei[N_EDGES + e]], 1);
}

__global__ __launch_bounds__(1024) void scan_kernel(const int* __restrict__ cnt,
                                                    int* __restrict__ rp) {
    __shared__ int lds[1024];
    __shared__ int carry_s;
    int tid = threadIdx.x;
    if (tid == 0) carry_s = 0;
    __syncthreads();
    for (int base = 0; base < N_NODES; base += 1024) {
        int v = (base + tid < N_NODES) ? cnt[base + tid] : 0;
        lds[tid] = v;
        __syncthreads();
        int sum = v;
        for (int off = 1; off < 1024; off <<= 1) {
            int t = (tid >= off) ? lds[tid - off] : 0;
            __syncthreads();
            sum += t;
            lds[tid] = sum;
            __syncthreads();
        }
        int carry = carry_s;
        if (base + tid < N_NODES) rp[base + tid] = carry + sum - v;
        __syncthreads();
        if (tid == 1023) carry_s = carry + sum;
        __syncthreads();
    }
    if (tid == 0) rp[N_NODES] = carry_s;
}

__global__ void fill_kernel(const int* __restrict__ ei, const int* __restrict__ rp,
                            int* __restrict__ cur, int* __restrict__ el) {
    int e = blockIdx.x * 256 + threadIdx.x;
    if (e < N_EDGES) {
        int d = ei[N_EDGES + e];
        int p = atomicAdd(&cur[d], 1);
        el[rp[d] + p] = ei[e];
    }
}

// ---------------- weight repack: Wcat[l][c][j], j<128: A'(W1 top), <256: B(W1 bot), else Wr
__global__ void repack_kernel(const float* __restrict__ W1, const float* __restrict__ Wr,
                              float* __restrict__ Wc) {
    int t = blockIdx.x * 256 + threadIdx.x;
    if (t >= 3 * 64 * 320) return;
    int l = t / (64 * 320);
    int rem = t % (64 * 320);
    int c = rem / 320, j = rem % 320;
    float v;
    if (j < 128)      v = W1[(l * 128 + c) * 128 + j];
    else if (j < 256) v = W1[(l * 128 + 64 + c) * 128 + (j - 128)];
    else              v = Wr[(l * 64 + c) * 64 + (j - 256)];
    Wc[t] = v;
}

// ---------------- encoder: x(N,32) @ encW(32,64) + b -> LN -> d_out
__global__ __launch_bounds__(256) void encoder_kernel(
    const float* __restrict__ x, const float* __restrict__ W,
    const float* __restrict__ b, const float* __restrict__ g,
    const float* __restrict__ beta, float* __restrict__ out) {
    __shared__ float wlds[IN_CH * M_CH];
    for (int t = threadIdx.x; t < IN_CH * M_CH; t += 256) wlds[t] = W[t];
    __syncthreads();
    int lane = threadIdx.x & 63;
    int node = blockIdx.x * 4 + (threadIdx.x >> 6);
    if (node >= N_NODES) return;
    float xv = (lane < IN_CH) ? x[node * IN_CH + lane] : 0.f;
    float acc = b[lane];
    #pragma unroll
    for (int c = 0; c < IN_CH; ++c) {
        float xc = __shfl(xv, c, 64);
        acc += xc * wlds[c * M_CH + lane];
    }
    float s = acc;
    for (int off = 32; off; off >>= 1) s += __shfl_xor(s, off, 64);
    float mu = s * (1.f / 64.f);
    float d = acc - mu;
    float q = d * d;
    for (int off = 32; off; off >>= 1) q += __shfl_xor(q, off, 64);
    float r = rsqrtf(q * (1.f / 64.f) + EPS);
    out[node * M_CH + lane] = d * r * g[lane] + beta[lane];
}

// ---------------- per-layer pre-norm: h = relu(LN(x))
__global__ __launch_bounds__(256) void ln_relu_kernel(
    const float* __restrict__ x, const float* __restrict__ g,
    const float* __restrict__ b, float* __restrict__ h) {
    int lane = threadIdx.x & 63;
    int node = blockIdx.x * 4 + (threadIdx.x >> 6);
    if (node >= N_NODES) return;
    float v = x[node * 64 + lane];
    float s = v;
    for (int off = 32; off; off >>= 1) s += __shfl_xor(s, off, 64);
    float mu = s * (1.f / 64.f);
    float d = v - mu;
    float q = d * d;
    for (int off = 32; off; off >>= 1) q += __shfl_xor(q, off, 64);
    float r = rsqrtf(q * (1.f / 64.f) + EPS);
    float hv = d * r * g[lane] + b[lane];
    h[node * 64 + lane] = fmaxf(hv, 0.f);
}

// ---------------- node GEMM: ABW(N,320) = h(N,64) @ Wc(64,320), +b1 on cols<128
#define TILE_M 16
__global__ __launch_bounds__(256) void gemm_kernel(
    const float* __restrict__ h, const float* __restrict__ Wc,
    const float* __restrict__ b1, float* __restrict__ ABW) {
    __shared__ float hl[TILE_M * 64];
    __shared__ float wl[16 * 320];
    int tid = threadIdx.x;
    int base = blockIdx.x * TILE_M;
    for (int t = tid; t < TILE_M * 64; t += 256) {
        int gi = base * 64 + t;
        hl[t] = (gi < N_NODES * 64) ? h[gi] : 0.f;
    }
    int r = tid >> 4;
    int j0 = (tid & 15) * 20;
    float acc[20];
    #pragma unroll
    for (int t = 0; t < 20; ++t) acc[t] = 0.f;
    for (int kk = 0; kk < 64; kk += 16) {
        __syncthreads();
        for (int t = tid; t < 16 * 320; t += 256) wl[t] = Wc[kk * 320 + t];
        __syncthreads();
        #pragma unroll
        for (int k = 0; k < 16; ++k) {
            float a = hl[r * 64 + kk + k];
            #pragma unroll
            for (int t = 0; t < 20; ++t) acc[t] += a * wl[k * 320 + j0 + t];
        }
    }
    int node = base + r;
    if (node < N_NODES) {
        #pragma unroll
        for (int t = 0; t < 20; ++t) {
            int j = j0 + t;
            ABW[node * 320 + j] = acc[t] + (j < 128 ? b1[j] : 0.f);
        }
    }
}

// ---------------- edge aggregate + W2 GEMV + residual update
__global__ __launch_bounds__(256) void edge_kernel(
    const float* __restrict__ ABW, const int* __restrict__ rp,
    const int* __restrict__ el, const float* __restrict__ W2,
    const float* __restrict__ b2, float* __restrict__ x) {
    __shared__ float w2l[128 * 64];
    for (int t = threadIdx.x; t < 128 * 64; t += 256) w2l[t] = W2[t];
    __syncthreads();
    int lane = threadIdx.x & 63;
    int gw = blockIdx.x * 4 + (threadIdx.x >> 6);
    int nw = gridDim.x * 4;
    for (int i = gw; i < N_NODES; i += nw) {
        float2 a = ((const float2*)(ABW + (size_t)i * 320))[lane];
        int s0 = rp[i], s1 = rp[i + 1];
        int cnt = s1 - s0;
        float2 acc = {0.f, 0.f};
        for (int e = s0; e < s1; ++e) {
            int s = el[e];
            float2 bb = ((const float2*)(ABW + (size_t)s * 320 + 128))[lane];
            acc.x += fmaxf(a.x + bb.x, 0.f);
            acc.y += fmaxf(a.y + bb.y, 0.f);
        }
        float aggj = 0.f;
        #pragma unroll 8
        for (int k2 = 0; k2 < 64; ++k2) {
            float sx = __shfl(acc.x, k2, 64);
            float sy = __shfl(acc.y, k2, 64);
            aggj += sx * w2l[(2 * k2) * 64 + lane] + sy * w2l[(2 * k2 + 1) * 64 + lane];
        }
        float deg = (float)(cnt > 0 ? cnt : 1);
        float val = aggj / deg + (cnt > 0 ? b2[lane] : 0.f);
        x[i * 64 + lane] += val + ABW[(size_t)i * 320 + 256 + lane];
    }
}

extern "C" void kernel_launch(void* const* d_in, const int* in_sizes, int n_in,
                              void* d_out, int out_size, void* d_ws, size_t ws_size,
                              hipStream_t stream) {
    const float* x       = (const float*)d_in[0];
    const int*   ei      = (const int*)d_in[1];
    const float* encW    = (const float*)d_in[2];
    const float* encb    = (const float*)d_in[3];
    const float* encg    = (const float*)d_in[4];
    const float* encbeta = (const float*)d_in[5];
    const float* lng     = (const float*)d_in[6];
    const float* lnb     = (const float*)d_in[7];
    const float* W1      = (const float*)d_in[8];
    const float* b1      = (const float*)d_in[9];
    const float* W2      = (const float*)d_in[10];
    const float* b2      = (const float*)d_in[11];
    const float* Wr      = (const float*)d_in[12];
    float* xout = (float*)d_out;

    char* ws = (char*)d_ws;
    size_t off = 0;
    auto alloc = [&](size_t bytes) -> void* {
        void* p = ws + off;
        off += (bytes + 255) & ~(size_t)255;
        return p;
    };
    float* Wcat = (float*)alloc(3 * 64 * 320 * sizeof(float));
    float* h    = (float*)alloc((size_t)N_NODES * 64 * sizeof(float));
    float* ABW  = (float*)alloc((size_t)N_NODES * 320 * sizeof(float));
    int*   cnt  = (int*)alloc(N_NODES * sizeof(int));
    int*   rp   = (int*)alloc((N_NODES + 1) * sizeof(int));
    int*   el   = (int*)alloc(N_EDGES * sizeof(int));

    hipMemsetAsync(cnt, 0, N_NODES * sizeof(int), stream);
    hist_kernel<<<(N_EDGES + 255) / 256, 256, 0, stream>>>(ei, cnt);
    scan_kernel<<<1, 1024, 0, stream>>>(cnt, rp);
    hipMemsetAsync(cnt, 0, N_NODES * sizeof(int), stream);
    fill_kernel<<<(N_EDGES + 255) / 256, 256, 0, stream>>>(ei, rp, cnt, el);
    repack_kernel<<<(3 * 64 * 320 + 255) / 256, 256, 0, stream>>>(W1, Wr, Wcat);

    encoder_kernel<<<(N_NODES + 3) / 4, 256, 0, stream>>>(x, encW, encb, encg, encbeta, xout);

    for (int l = 0; l < 3; ++l) {
        ln_relu_kernel<<<(N_NODES + 3) / 4, 256, 0, stream>>>(
            xout, lng + l * 64, lnb + l * 64, h);
        gemm_kernel<<<(N_NODES + TILE_M - 1) / TILE_M, 256, 0, stream>>>(
            h, Wcat + l * 64 * 320, b1 + l * 128, ABW);
        edge_kernel<<<1024, 256, 0, stream>>>(
            ABW, rp, el, W2 + l * 128 * 64, b2 + l * 64, xout);
    }
}

// Round 2
// 633.375 us; speedup vs baseline: 1.3087x; 1.3087x over previous
//
#include <hip/hip_runtime.h>
#include <hip/hip_bf16.h>

#define N_NODES 50000
#define N_EDGES 400000
#define IN_CH 32
#define M_CH 64
#define EPS 1e-5f
#define SCAN_NB ((N_NODES + 1023) / 1024)

static __device__ __forceinline__ unsigned short f2bf(float f) {
    __hip_bfloat16 h = __float2bfloat16(f);
    return *(unsigned short*)&h;
}

// ---------------- CSR build ----------------
__global__ void hist_kernel(const int* __restrict__ ei, int* __restrict__ cnt) {
    int e = blockIdx.x * 256 + threadIdx.x;
    if (e < N_EDGES) atomicAdd(&cnt[ei[N_EDGES + e]], 1);
}

// hierarchical scan: per-block exclusive scan + block sums
__global__ __launch_bounds__(1024) void scan1_kernel(const int* __restrict__ cnt,
                                                     int* __restrict__ exw,
                                                     int* __restrict__ bsum) {
    int b = blockIdx.x, t = threadIdx.x;
    int i = b * 1024 + t;
    int v = (i < N_NODES) ? cnt[i] : 0;
    int lane = t & 63, w = t >> 6;
    int s = v;
    #pragma unroll
    for (int off = 1; off < 64; off <<= 1) {
        int u = __shfl_up(s, off, 64);
        if (lane >= off) s += u;
    }
    __shared__ int ws[16];
    if (lane == 63) ws[w] = s;
    __syncthreads();
    if (t < 16) {
        int sv = ws[t];
        #pragma unroll
        for (int off = 1; off < 16; off <<= 1) {
            int u = __shfl_up(sv, off, 64);
            if (lane >= off) sv += u;
        }
        ws[t] = sv;
    }
    __syncthreads();
    int prefix = (w > 0) ? ws[w - 1] : 0;
    int incl = s + prefix;
    if (i < N_NODES) exw[i] = incl - v;
    if (t == 1023) bsum[b] = incl;
}

__global__ void scan2_kernel(int* __restrict__ bsum) {
    int t = threadIdx.x;  // single wave of 64
    int v = (t < SCAN_NB) ? bsum[t] : 0;
    #pragma unroll
    for (int off = 1; off < 64; off <<= 1) {
        int u = __shfl_up(v, off, 64);
        if (t >= off) v += u;
    }
    if (t < SCAN_NB) bsum[t] = v;
}

__global__ __launch_bounds__(1024) void scan3_kernel(const int* __restrict__ exw,
                                                     const int* __restrict__ bsum,
                                                     int* __restrict__ rp) {
    int b = blockIdx.x, t = threadIdx.x;
    int i = b * 1024 + t;
    if (i < N_NODES) rp[i] = exw[i] + (b > 0 ? bsum[b - 1] : 0);
    if (b == 0 && t == 0) rp[N_NODES] = bsum[SCAN_NB - 1];
}

__global__ void fill_kernel(const int* __restrict__ ei, const int* __restrict__ rp,
                            int* __restrict__ cur, int* __restrict__ el) {
    int e = blockIdx.x * 256 + threadIdx.x;
    if (e < N_EDGES) {
        int d = ei[N_EDGES + e];
        int p = atomicAdd(&cur[d], 1);
        el[rp[d] + p] = ei[e];
    }
}

// ---------------- weight repack: Wcat[l][c][j], j<128: W1 top, <256: W1 bot, else Wr
__global__ void repack_kernel(const float* __restrict__ W1, const float* __restrict__ Wr,
                              float* __restrict__ Wc) {
    int t = blockIdx.x * 256 + threadIdx.x;
    if (t >= 3 * 64 * 320) return;
    int l = t / (64 * 320);
    int rem = t % (64 * 320);
    int c = rem / 320, j = rem % 320;
    float v;
    if (j < 128)      v = W1[(l * 128 + c) * 128 + j];
    else if (j < 256) v = W1[(l * 128 + 64 + c) * 128 + (j - 128)];
    else              v = Wr[(l * 64 + c) * 64 + (j - 256)];
    Wc[t] = v;
}

// ---------------- encoder: x(N,32) @ encW(32,64) + b -> LN -> d_out
__global__ __launch_bounds__(256) void encoder_kernel(
    const float* __restrict__ x, const float* __restrict__ W,
    const float* __restrict__ b, const float* __restrict__ g,
    const float* __restrict__ beta, float* __restrict__ out) {
    __shared__ float wlds[IN_CH * M_CH];
    for (int t = threadIdx.x; t < IN_CH * M_CH; t += 256) wlds[t] = W[t];
    __syncthreads();
    int lane = threadIdx.x & 63;
    int node = blockIdx.x * 4 + (threadIdx.x >> 6);
    if (node >= N_NODES) return;
    float xv = (lane < IN_CH) ? x[node * IN_CH + lane] : 0.f;
    float acc = b[lane];
    #pragma unroll
    for (int c = 0; c < IN_CH; ++c) {
        float xc = __shfl(xv, c, 64);
        acc += xc * wlds[c * M_CH + lane];
    }
    float s = acc;
    for (int off = 32; off; off >>= 1) s += __shfl_xor(s, off, 64);
    float mu = s * (1.f / 64.f);
    float d = acc - mu;
    float q = d * d;
    for (int off = 32; off; off >>= 1) q += __shfl_xor(q, off, 64);
    float r = rsqrtf(q * (1.f / 64.f) + EPS);
    out[node * M_CH + lane] = d * r * g[lane] + beta[lane];
}

// ---------------- fused LN+ReLU + node GEMM:
// h = relu(LN(x));  [A128 | B64(bf16 pairs) | R64] = h @ Wc  (+b1 on A cols)
#define TILE_M 16
__global__ __launch_bounds__(256) void gemm_kernel(
    const float* __restrict__ x, const float* __restrict__ g,
    const float* __restrict__ bvec, const float* __restrict__ Wc,
    const float* __restrict__ b1, float* __restrict__ A128,
    unsigned int* __restrict__ B64, float* __restrict__ R64) {
    __shared__ float hl[TILE_M * 64];
    __shared__ float wl[16 * 320];
    int tid = threadIdx.x;
    int lane = tid & 63, w = tid >> 6;
    int base = blockIdx.x * TILE_M;
    // fused LN + relu: 4 waves x 4 nodes
    #pragma unroll
    for (int n = 0; n < 4; ++n) {
        int node = base + w * 4 + n;
        float v = (node < N_NODES) ? x[node * 64 + lane] : 0.f;
        float s = v;
        for (int off = 32; off; off >>= 1) s += __shfl_xor(s, off, 64);
        float mu = s * (1.f / 64.f);
        float d = v - mu;
        float q = d * d;
        for (int off = 32; off; off >>= 1) q += __shfl_xor(q, off, 64);
        float r = rsqrtf(q * (1.f / 64.f) + EPS);
        float hv = d * r * g[lane] + bvec[lane];
        hl[(w * 4 + n) * 64 + lane] = fmaxf(hv, 0.f);
    }
    int r = tid >> 4;
    int j0 = (tid & 15) * 20;
    float acc[20];
    #pragma unroll
    for (int t = 0; t < 20; ++t) acc[t] = 0.f;
    for (int kk = 0; kk < 64; kk += 16) {
        __syncthreads();
        for (int t = tid; t < 16 * 320; t += 256) wl[t] = Wc[kk * 320 + t];
        __syncthreads();
        #pragma unroll
        for (int k = 0; k < 16; ++k) {
            float a = hl[r * 64 + kk + k];
            #pragma unroll
            for (int t = 0; t < 20; ++t) acc[t] += a * wl[k * 320 + j0 + t];
        }
    }
    int node = base + r;
    if (node < N_NODES) {
        #pragma unroll
        for (int t = 0; t < 20; ++t) {
            int j = j0 + t;
            if (j < 128) {
                A128[(size_t)node * 128 + j] = acc[t] + b1[j];
            } else if (j < 256) {
                if (((j - 128) & 1) == 0) {  // pack pair (j, j+1); ranges are pair-aligned
                    unsigned int lo = f2bf(acc[t]);
                    unsigned int hi = f2bf(acc[t + 1]);
                    B64[(size_t)node * 64 + ((j - 128) >> 1)] = (hi << 16) | lo;
                }
            } else {
                R64[(size_t)node * 64 + (j - 256)] = acc[t];
            }
        }
    }
}

// ---------------- edge aggregate + W2 GEMV + residual update
__global__ __launch_bounds__(256) void edge_kernel(
    const float* __restrict__ A128, const unsigned int* __restrict__ B64,
    const float* __restrict__ R64, const int* __restrict__ rp,
    const int* __restrict__ el, const float* __restrict__ W2,
    const float* __restrict__ b2, float* __restrict__ x) {
    __shared__ unsigned int w2p[64 * 64];  // 16 KB: rows (2k2,2k2+1) packed bf16
    for (int t = threadIdx.x; t < 64 * 64; t += 256) {
        int k2 = t >> 6, ln = t & 63;
        unsigned int lo = f2bf(W2[(2 * k2) * 64 + ln]);
        unsigned int hi = f2bf(W2[(2 * k2 + 1) * 64 + ln]);
        w2p[t] = (hi << 16) | lo;
    }
    __syncthreads();
    int lane = threadIdx.x & 63;
    float bb2 = b2[lane];
    int gw = blockIdx.x * 4 + (threadIdx.x >> 6);
    int nw = gridDim.x * 4;
    for (int i = gw; i < N_NODES; i += nw) {
        float2 a = ((const float2*)(A128 + (size_t)i * 128))[lane];
        int s0 = rp[i], s1 = rp[i + 1];
        int cnt = s1 - s0;
        float2 acc = {0.f, 0.f};
        for (int e = s0; e < s1; ++e) {
            int s = el[e];
            unsigned int u = B64[(size_t)s * 64 + lane];
            float bx = __uint_as_float(u << 16);
            float by = __uint_as_float(u & 0xffff0000u);
            acc.x += fmaxf(a.x + bx, 0.f);
            acc.y += fmaxf(a.y + by, 0.f);
        }
        float aggj = 0.f;
        #pragma unroll 8
        for (int k2 = 0; k2 < 64; ++k2) {
            float sx = __shfl(acc.x, k2, 64);
            float sy = __shfl(acc.y, k2, 64);
            unsigned int wp = w2p[k2 * 64 + lane];
            aggj += sx * __uint_as_float(wp << 16) + sy * __uint_as_float(wp & 0xffff0000u);
        }
        float deg = (float)(cnt > 0 ? cnt : 1);
        float val = aggj / deg + (cnt > 0 ? bb2 : 0.f);
        x[i * 64 + lane] += val + R64[(size_t)i * 64 + lane];
    }
}

extern "C" void kernel_launch(void* const* d_in, const int* in_sizes, int n_in,
                              void* d_out, int out_size, void* d_ws, size_t ws_size,
                              hipStream_t stream) {
    const float* x       = (const float*)d_in[0];
    const int*   ei      = (const int*)d_in[1];
    const float* encW    = (const float*)d_in[2];
    const float* encb    = (const float*)d_in[3];
    const float* encg    = (const float*)d_in[4];
    const float* encbeta = (const float*)d_in[5];
    const float* lng     = (const float*)d_in[6];
    const float* lnb     = (const float*)d_in[7];
    const float* W1      = (const float*)d_in[8];
    const float* b1      = (const float*)d_in[9];
    const float* W2      = (const float*)d_in[10];
    const float* b2      = (const float*)d_in[11];
    const float* Wr      = (const float*)d_in[12];
    float* xout = (float*)d_out;

    char* ws = (char*)d_ws;
    size_t off = 0;
    auto alloc = [&](size_t bytes) -> void* {
        void* p = ws + off;
        off += (bytes + 255) & ~(size_t)255;
        return p;
    };
    float*        Wcat = (float*)alloc(3 * 64 * 320 * sizeof(float));
    float*        A128 = (float*)alloc((size_t)N_NODES * 128 * sizeof(float));
    unsigned int* B64  = (unsigned int*)alloc((size_t)N_NODES * 64 * sizeof(unsigned int));
    float*        R64  = (float*)alloc((size_t)N_NODES * 64 * sizeof(float));
    int*          cnt  = (int*)alloc(N_NODES * sizeof(int));
    int*          rp   = (int*)alloc((N_NODES + 1) * sizeof(int));
    int*          el   = (int*)alloc(N_EDGES * sizeof(int));
    int*          exw  = (int*)alloc(N_NODES * sizeof(int));
    int*          bsum = (int*)alloc(SCAN_NB * sizeof(int));

    hipMemsetAsync(cnt, 0, N_NODES * sizeof(int), stream);
    hist_kernel<<<(N_EDGES + 255) / 256, 256, 0, stream>>>(ei, cnt);
    scan1_kernel<<<SCAN_NB, 1024, 0, stream>>>(cnt, exw, bsum);
    scan2_kernel<<<1, 64, 0, stream>>>(bsum);
    scan3_kernel<<<SCAN_NB, 1024, 0, stream>>>(exw, bsum, rp);
    hipMemsetAsync(cnt, 0, N_NODES * sizeof(int), stream);
    fill_kernel<<<(N_EDGES + 255) / 256, 256, 0, stream>>>(ei, rp, cnt, el);
    repack_kernel<<<(3 * 64 * 320 + 255) / 256, 256, 0, stream>>>(W1, Wr, Wcat);

    encoder_kernel<<<(N_NODES + 3) / 4, 256, 0, stream>>>(x, encW, encb, encg, encbeta, xout);

    for (int l = 0; l < 3; ++l) {
        gemm_kernel<<<(N_NODES + TILE_M - 1) / TILE_M, 256, 0, stream>>>(
            xout, lng + l * 64, lnb + l * 64, Wcat + l * 64 * 320, b1 + l * 128,
            A128, B64, R64);
        edge_kernel<<<2048, 256, 0, stream>>>(
            A128, B64, R64, rp, el, W2 + l * 128 * 64, b2 + l * 64, xout);
    }
}

// Round 3
// 594.635 us; speedup vs baseline: 1.3939x; 1.0651x over previous
//
#include <hip/hip_runtime.h>
#include <hip/hip_bf16.h>

#define N_NODES 50000
#define N_EDGES 400000
#define IN_CH 32
#define EPS 1e-5f
#define SCAN_NB ((N_NODES + 1023) / 1024)

static __device__ __forceinline__ unsigned int f2bf(float f) {
    __hip_bfloat16 h = __float2bfloat16(f);
    return (unsigned int)*(unsigned short*)&h;
}
static __device__ __forceinline__ float bflo(unsigned int u) { return __uint_as_float(u << 16); }
static __device__ __forceinline__ float bfhi(unsigned int u) { return __uint_as_float(u & 0xffff0000u); }

// ---------------- CSR build ----------------
__global__ void hist_kernel(const int* __restrict__ ei, int* __restrict__ cnt) {
    int e = blockIdx.x * 256 + threadIdx.x;
    if (e < N_EDGES) atomicAdd(&cnt[ei[N_EDGES + e]], 1);
}

__global__ __launch_bounds__(1024) void scan1_kernel(const int* __restrict__ cnt,
                                                     int* __restrict__ exw,
                                                     int* __restrict__ bsum) {
    int b = blockIdx.x, t = threadIdx.x;
    int i = b * 1024 + t;
    int v = (i < N_NODES) ? cnt[i] : 0;
    int lane = t & 63, w = t >> 6;
    int s = v;
    #pragma unroll
    for (int off = 1; off < 64; off <<= 1) {
        int u = __shfl_up(s, off, 64);
        if (lane >= off) s += u;
    }
    __shared__ int ws[16];
    if (lane == 63) ws[w] = s;
    __syncthreads();
    if (t < 16) {
        int sv = ws[t];
        #pragma unroll
        for (int off = 1; off < 16; off <<= 1) {
            int u = __shfl_up(sv, off, 64);
            if (lane >= off) sv += u;
        }
        ws[t] = sv;
    }
    __syncthreads();
    int prefix = (w > 0) ? ws[w - 1] : 0;
    int incl = s + prefix;
    if (i < N_NODES) exw[i] = incl - v;
    if (t == 1023) bsum[b] = incl;
}

__global__ void scan2_kernel(int* __restrict__ bsum) {
    int t = threadIdx.x;
    int v = (t < SCAN_NB) ? bsum[t] : 0;
    #pragma unroll
    for (int off = 1; off < 64; off <<= 1) {
        int u = __shfl_up(v, off, 64);
        if (t >= off) v += u;
    }
    if (t < SCAN_NB) bsum[t] = v;
}

__global__ __launch_bounds__(1024) void scan3_kernel(const int* __restrict__ exw,
                                                     const int* __restrict__ bsum,
                                                     int* __restrict__ rp) {
    int b = blockIdx.x, t = threadIdx.x;
    int i = b * 1024 + t;
    if (i < N_NODES) rp[i] = exw[i] + (b > 0 ? bsum[b - 1] : 0);
    if (b == 0 && t == 0) rp[N_NODES] = bsum[SCAN_NB - 1];
}

__global__ void fill_kernel(const int* __restrict__ ei, const int* __restrict__ rp,
                            int* __restrict__ cur, int* __restrict__ el) {
    int e = blockIdx.x * 256 + threadIdx.x;
    if (e < N_EDGES) {
        int d = ei[N_EDGES + e];
        int p = atomicAdd(&cur[d], 1);
        el[rp[d] + p] = ei[e];
    }
}

// ---------------- weight repack: Wcat[l][c][j], j<128: W1 top, <256: W1 bot, else Wr
__global__ void repack_kernel(const float* __restrict__ W1, const float* __restrict__ Wr,
                              float* __restrict__ Wc) {
    int t = blockIdx.x * 256 + threadIdx.x;
    if (t >= 3 * 64 * 320) return;
    int l = t / (64 * 320);
    int rem = t % (64 * 320);
    int c = rem / 320, j = rem % 320;
    float v;
    if (j < 128)      v = W1[(l * 128 + c) * 128 + j];
    else if (j < 256) v = W1[(l * 128 + 64 + c) * 128 + (j - 128)];
    else              v = Wr[(l * 64 + c) * 64 + (j - 256)];
    Wc[t] = v;
}

// ---------------- encoder
__global__ __launch_bounds__(256) void encoder_kernel(
    const float* __restrict__ x, const float* __restrict__ W,
    const float* __restrict__ b, const float* __restrict__ g,
    const float* __restrict__ beta, float* __restrict__ out) {
    __shared__ float wlds[IN_CH * 64];
    for (int t = threadIdx.x; t < IN_CH * 64; t += 256) wlds[t] = W[t];
    __syncthreads();
    int lane = threadIdx.x & 63;
    int node = blockIdx.x * 4 + (threadIdx.x >> 6);
    if (node >= N_NODES) return;
    float xv = (lane < IN_CH) ? x[node * IN_CH + lane] : 0.f;
    float acc = b[lane];
    #pragma unroll
    for (int c = 0; c < IN_CH; ++c) {
        float xc = __shfl(xv, c, 64);
        acc += xc * wlds[c * 64 + lane];
    }
    float s = acc;
    for (int off = 32; off; off >>= 1) s += __shfl_xor(s, off, 64);
    float mu = s * (1.f / 64.f);
    float d = acc - mu;
    float q = d * d;
    for (int off = 32; off; off >>= 1) q += __shfl_xor(q, off, 64);
    float r = rsqrtf(q * (1.f / 64.f) + EPS);
    out[node * 64 + lane] = d * r * g[lane] + beta[lane];
}

// ---------------- fused: [optional update x += S/deg@W2 + b2 + R] -> LN+ReLU -> GEMM
#define TM 64
__global__ __launch_bounds__(256) void fused_kernel(
    float* x, const unsigned int* __restrict__ S,
    const float* __restrict__ W2, const float* __restrict__ b2,
    const int* __restrict__ rp, const float* __restrict__ g,
    const float* __restrict__ bvec, const float* __restrict__ Wc,
    const float* __restrict__ b1, float* __restrict__ A128,
    unsigned int* __restrict__ B64, float* R64, int do_update) {
    __shared__ unsigned int sl[64 * 65];
    __shared__ unsigned int w2l[64 * 64];
    __shared__ float xl[64 * 68];
    __shared__ float wl[8 * 320];
    int tid = threadIdx.x;
    int lane = tid & 63, wid = tid >> 6;
    int base = blockIdx.x * TM;
    int rg = tid >> 4, cg = tid & 15;
    int r0 = rg * 4;
    int j1 = cg * 4;   // stage-1 cols
    int j2 = cg * 20;  // stage-2 cols

    if (do_update) {
        for (int t = tid; t < 64 * 64; t += 256) {
            int row = t >> 6, k = t & 63;
            int node = base + row;
            sl[row * 65 + k] = (node < N_NODES) ? S[(size_t)node * 64 + k] : 0u;
        }
        for (int t = tid; t < 64 * 64; t += 256) {
            int k2 = t >> 6, c = t & 63;
            w2l[t] = f2bf(W2[(2 * k2) * 64 + c]) | (f2bf(W2[(2 * k2 + 1) * 64 + c]) << 16);
        }
        __syncthreads();
        float acc1[4][4] = {{0.f}};
        #pragma unroll 4
        for (int k2 = 0; k2 < 64; ++k2) {
            float sx[4], sy[4];
            #pragma unroll
            for (int r = 0; r < 4; ++r) {
                unsigned int u = sl[(r0 + r) * 65 + k2];
                sx[r] = bflo(u); sy[r] = bfhi(u);
            }
            uint4 wv = *(const uint4*)&w2l[k2 * 64 + j1];
            float wx0 = bflo(wv.x), wy0 = bfhi(wv.x);
            float wx1 = bflo(wv.y), wy1 = bfhi(wv.y);
            float wx2 = bflo(wv.z), wy2 = bfhi(wv.z);
            float wx3 = bflo(wv.w), wy3 = bfhi(wv.w);
            #pragma unroll
            for (int r = 0; r < 4; ++r) {
                acc1[r][0] += sx[r] * wx0 + sy[r] * wy0;
                acc1[r][1] += sx[r] * wx1 + sy[r] * wy1;
                acc1[r][2] += sx[r] * wx2 + sy[r] * wy2;
                acc1[r][3] += sx[r] * wx3 + sy[r] * wy3;
            }
        }
        float4 bb = *(const float4*)&b2[j1];
        #pragma unroll
        for (int r = 0; r < 4; ++r) {
            int node = base + r0 + r;
            if (node < N_NODES) {
                int c0 = rp[node], c1 = rp[node + 1];
                int cv = c1 - c0;
                float inv = cv > 0 ? 1.f / (float)cv : 0.f;
                float msk = cv > 0 ? 1.f : 0.f;
                float4 xo = *(const float4*)&x[(size_t)node * 64 + j1];
                float4 ro = *(const float4*)&R64[(size_t)node * 64 + j1];
                float4 xn;
                xn.x = xo.x + acc1[r][0] * inv + bb.x * msk + ro.x;
                xn.y = xo.y + acc1[r][1] * inv + bb.y * msk + ro.y;
                xn.z = xo.z + acc1[r][2] * inv + bb.z * msk + ro.z;
                xn.w = xo.w + acc1[r][3] * inv + bb.w * msk + ro.w;
                *(float4*)&x[(size_t)node * 64 + j1] = xn;
                *(float4*)&xl[(r0 + r) * 68 + j1] = xn;
            }
        }
    } else {
        #pragma unroll
        for (int r = 0; r < 4; ++r) {
            int node = base + r0 + r;
            if (node < N_NODES) {
                float4 xo = *(const float4*)&x[(size_t)node * 64 + j1];
                *(float4*)&xl[(r0 + r) * 68 + j1] = xo;
            }
        }
    }
    __syncthreads();
    // LN + ReLU in place (each wave owns 16 rows)
    {
        float gv = g[lane], bv = bvec[lane];
        for (int n = 0; n < 16; ++n) {
            int row = wid * 16 + n;
            float v = xl[row * 68 + lane];
            float s = v;
            for (int off = 32; off; off >>= 1) s += __shfl_xor(s, off, 64);
            float mu = s * (1.f / 64.f);
            float d = v - mu;
            float q = d * d;
            for (int off = 32; off; off >>= 1) q += __shfl_xor(q, off, 64);
            float rs = rsqrtf(q * (1.f / 64.f) + EPS);
            xl[row * 68 + lane] = fmaxf(d * rs * gv + bv, 0.f);
        }
    }
    // stage-2 GEMM: 4 rows x 20 cols per thread, K chunks of 8
    float acc2[4][20];
    #pragma unroll
    for (int r = 0; r < 4; ++r)
        #pragma unroll
        for (int t = 0; t < 20; ++t) acc2[r][t] = 0.f;
    for (int kk = 0; kk < 64; kk += 8) {
        __syncthreads();
        for (int t = tid; t < 8 * 320 / 4; t += 256)
            ((float4*)wl)[t] = ((const float4*)(Wc + kk * 320))[t];
        __syncthreads();
        #pragma unroll
        for (int k = 0; k < 8; ++k) {
            float av[4];
            #pragma unroll
            for (int r = 0; r < 4; ++r) av[r] = xl[(r0 + r) * 68 + kk + k];
            #pragma unroll
            for (int c5 = 0; c5 < 5; ++c5) {
                float4 w4 = *(const float4*)&wl[k * 320 + j2 + c5 * 4];
                #pragma unroll
                for (int r = 0; r < 4; ++r) {
                    acc2[r][c5 * 4 + 0] += av[r] * w4.x;
                    acc2[r][c5 * 4 + 1] += av[r] * w4.y;
                    acc2[r][c5 * 4 + 2] += av[r] * w4.z;
                    acc2[r][c5 * 4 + 3] += av[r] * w4.w;
                }
            }
        }
    }
    #pragma unroll
    for (int r = 0; r < 4; ++r) {
        int node = base + r0 + r;
        if (node >= N_NODES) continue;
        #pragma unroll
        for (int t = 0; t < 20; ++t) {
            int j = j2 + t;
            float v = acc2[r][t];
            if (j < 128) {
                A128[(size_t)node * 128 + j] = v + b1[j];
            } else if (j < 256) {
                if ((j & 1) == 0)
                    B64[(size_t)node * 64 + ((j - 128) >> 1)] =
                        f2bf(v) | (f2bf(acc2[r][t + 1]) << 16);
            } else {
                R64[(size_t)node * 64 + (j - 256)] = v;
            }
        }
    }
}

// ---------------- pure edge aggregation: S[i] = sum_src relu(A[i] + B[src]) (bf16 packed)
__global__ __launch_bounds__(256) void edge_agg_kernel(
    const float* __restrict__ A128, const unsigned int* __restrict__ B64,
    const int* __restrict__ rp, const int* __restrict__ el,
    unsigned int* __restrict__ S) {
    int lane = threadIdx.x & 63;
    int i = blockIdx.x * 4 + (threadIdx.x >> 6);
    if (i >= N_NODES) return;
    float2 a = ((const float2*)(A128 + (size_t)i * 128))[lane];
    int s0 = rp[i], s1 = rp[i + 1];
    float ax = 0.f, ay = 0.f;
    int e = s0;
    for (; e + 4 <= s1; e += 4) {
        int n0 = el[e], n1 = el[e + 1], n2 = el[e + 2], n3 = el[e + 3];
        unsigned int u0 = B64[(size_t)n0 * 64 + lane];
        unsigned int u1 = B64[(size_t)n1 * 64 + lane];
        unsigned int u2 = B64[(size_t)n2 * 64 + lane];
        unsigned int u3 = B64[(size_t)n3 * 64 + lane];
        ax += fmaxf(a.x + bflo(u0), 0.f) + fmaxf(a.x + bflo(u1), 0.f) +
              fmaxf(a.x + bflo(u2), 0.f) + fmaxf(a.x + bflo(u3), 0.f);
        ay += fmaxf(a.y + bfhi(u0), 0.f) + fmaxf(a.y + bfhi(u1), 0.f) +
              fmaxf(a.y + bfhi(u2), 0.f) + fmaxf(a.y + bfhi(u3), 0.f);
    }
    for (; e < s1; ++e) {
        int n = el[e];
        unsigned int u = B64[(size_t)n * 64 + lane];
        ax += fmaxf(a.x + bflo(u), 0.f);
        ay += fmaxf(a.y + bfhi(u), 0.f);
    }
    S[(size_t)i * 64 + lane] = f2bf(ax) | (f2bf(ay) << 16);
}

// ---------------- final update (after last edge pass): x += S/deg@W2 + b2*m + R
__global__ __launch_bounds__(256) void final_update_kernel(
    float* x, const unsigned int* __restrict__ S,
    const float* __restrict__ W2, const float* __restrict__ b2,
    const int* __restrict__ rp, const float* __restrict__ R64) {
    __shared__ unsigned int sl[64 * 65];
    __shared__ unsigned int w2l[64 * 64];
    int tid = threadIdx.x;
    int base = blockIdx.x * TM;
    int rg = tid >> 4, cg = tid & 15;
    int r0 = rg * 4, j1 = cg * 4;
    for (int t = tid; t < 64 * 64; t += 256) {
        int row = t >> 6, k = t & 63;
        int node = base + row;
        sl[row * 65 + k] = (node < N_NODES) ? S[(size_t)node * 64 + k] : 0u;
    }
    for (int t = tid; t < 64 * 64; t += 256) {
        int k2 = t >> 6, c = t & 63;
        w2l[t] = f2bf(W2[(2 * k2) * 64 + c]) | (f2bf(W2[(2 * k2 + 1) * 64 + c]) << 16);
    }
    __syncthreads();
    float acc1[4][4] = {{0.f}};
    #pragma unroll 4
    for (int k2 = 0; k2 < 64; ++k2) {
        float sx[4], sy[4];
        #pragma unroll
        for (int r = 0; r < 4; ++r) {
            unsigned int u = sl[(r0 + r) * 65 + k2];
            sx[r] = bflo(u); sy[r] = bfhi(u);
        }
        uint4 wv = *(const uint4*)&w2l[k2 * 64 + j1];
        float wx0 = bflo(wv.x), wy0 = bfhi(wv.x);
        float wx1 = bflo(wv.y), wy1 = bfhi(wv.y);
        float wx2 = bflo(wv.z), wy2 = bfhi(wv.z);
        float wx3 = bflo(wv.w), wy3 = bfhi(wv.w);
        #pragma unroll
        for (int r = 0; r < 4; ++r) {
            acc1[r][0] += sx[r] * wx0 + sy[r] * wy0;
            acc1[r][1] += sx[r] * wx1 + sy[r] * wy1;
            acc1[r][2] += sx[r] * wx2 + sy[r] * wy2;
            acc1[r][3] += sx[r] * wx3 + sy[r] * wy3;
        }
    }
    float4 bb = *(const float4*)&b2[j1];
    #pragma unroll
    for (int r = 0; r < 4; ++r) {
        int node = base + r0 + r;
        if (node < N_NODES) {
            int c0 = rp[node], c1 = rp[node + 1];
            int cv = c1 - c0;
            float inv = cv > 0 ? 1.f / (float)cv : 0.f;
            float msk = cv > 0 ? 1.f : 0.f;
            float4 xo = *(const float4*)&x[(size_t)node * 64 + j1];
            float4 ro = *(const float4*)&R64[(size_t)node * 64 + j1];
            xo.x += acc1[r][0] * inv + bb.x * msk + ro.x;
            xo.y += acc1[r][1] * inv + bb.y * msk + ro.y;
            xo.z += acc1[r][2] * inv + bb.z * msk + ro.z;
            xo.w += acc1[r][3] * inv + bb.w * msk + ro.w;
            *(float4*)&x[(size_t)node * 64 + j1] = xo;
        }
    }
}

extern "C" void kernel_launch(void* const* d_in, const int* in_sizes, int n_in,
                              void* d_out, int out_size, void* d_ws, size_t ws_size,
                              hipStream_t stream) {
    const float* x       = (const float*)d_in[0];
    const int*   ei      = (const int*)d_in[1];
    const float* encW    = (const float*)d_in[2];
    const float* encb    = (const float*)d_in[3];
    const float* encg    = (const float*)d_in[4];
    const float* encbeta = (const float*)d_in[5];
    const float* lng     = (const float*)d_in[6];
    const float* lnb     = (const float*)d_in[7];
    const float* W1      = (const float*)d_in[8];
    const float* b1      = (const float*)d_in[9];
    const float* W2      = (const float*)d_in[10];
    const float* b2      = (const float*)d_in[11];
    const float* Wr      = (const float*)d_in[12];
    float* xout = (float*)d_out;

    char* ws = (char*)d_ws;
    size_t off = 0;
    auto alloc = [&](size_t bytes) -> void* {
        void* p = ws + off;
        off += (bytes + 255) & ~(size_t)255;
        return p;
    };
    float*        Wcat = (float*)alloc(3 * 64 * 320 * sizeof(float));
    float*        A128 = (float*)alloc((size_t)N_NODES * 128 * sizeof(float));
    unsigned int* B64  = (unsigned int*)alloc((size_t)N_NODES * 64 * sizeof(unsigned int));
    float*        R64  = (float*)alloc((size_t)N_NODES * 64 * sizeof(float));
    unsigned int* Sbuf = (unsigned int*)alloc((size_t)N_NODES * 64 * sizeof(unsigned int));
    int*          cnt  = (int*)alloc(N_NODES * sizeof(int));
    int*          rp   = (int*)alloc((N_NODES + 1) * sizeof(int));
    int*          el   = (int*)alloc(N_EDGES * sizeof(int));
    int*          exw  = (int*)alloc(N_NODES * sizeof(int));
    int*          bsum = (int*)alloc(SCAN_NB * sizeof(int));

    hipMemsetAsync(cnt, 0, N_NODES * sizeof(int), stream);
    hist_kernel<<<(N_EDGES + 255) / 256, 256, 0, stream>>>(ei, cnt);
    scan1_kernel<<<SCAN_NB, 1024, 0, stream>>>(cnt, exw, bsum);
    scan2_kernel<<<1, 64, 0, stream>>>(bsum);
    scan3_kernel<<<SCAN_NB, 1024, 0, stream>>>(exw, bsum, rp);
    hipMemsetAsync(cnt, 0, N_NODES * sizeof(int), stream);
    fill_kernel<<<(N_EDGES + 255) / 256, 256, 0, stream>>>(ei, rp, cnt, el);
    repack_kernel<<<(3 * 64 * 320 + 255) / 256, 256, 0, stream>>>(W1, Wr, Wcat);

    encoder_kernel<<<(N_NODES + 3) / 4, 256, 0, stream>>>(x, encW, encb, encg, encbeta, xout);

    int gblocks = (N_NODES + TM - 1) / TM;
    for (int l = 0; l < 3; ++l) {
        const float* w2p = (l > 0) ? (W2 + (size_t)(l - 1) * 128 * 64) : W2;
        const float* b2p = (l > 0) ? (b2 + (size_t)(l - 1) * 64) : b2;
        fused_kernel<<<gblocks, 256, 0, stream>>>(
            xout, Sbuf, w2p, b2p, rp, lng + l * 64, lnb + l * 64,
            Wcat + l * 64 * 320, b1 + l * 128, A128, B64, R64, l > 0 ? 1 : 0);
        edge_agg_kernel<<<(N_NODES + 3) / 4, 256, 0, stream>>>(A128, B64, rp, el, Sbuf);
    }
    final_update_kernel<<<gblocks, 256, 0, stream>>>(
        xout, Sbuf, W2 + (size_t)2 * 128 * 64, b2 + 2 * 64, rp, R64);
}

// Round 4
// 313.947 us; speedup vs baseline: 2.6402x; 1.8941x over previous
//
#include <hip/hip_runtime.h>
#include <hip/hip_bf16.h>

#define N_NODES 50000
#define N_EDGES 400000
#define IN_CH 32
#define EPS 1e-5f
#define SCAN_NB ((N_NODES + 1023) / 1024)

typedef __attribute__((ext_vector_type(8))) short bh8;
typedef __attribute__((ext_vector_type(4))) float fx4;

static __device__ __forceinline__ unsigned int f2bf(float f) {
    __hip_bfloat16 h = __float2bfloat16(f);
    return (unsigned int)*(unsigned short*)&h;
}
static __device__ __forceinline__ unsigned short f2bfu(float f) {
    __hip_bfloat16 h = __float2bfloat16(f);
    return *(unsigned short*)&h;
}
static __device__ __forceinline__ float bflo(unsigned int u) { return __uint_as_float(u << 16); }
static __device__ __forceinline__ float bfhi(unsigned int u) { return __uint_as_float(u & 0xffff0000u); }

// ---------------- CSR build ----------------
__global__ void hist_kernel(const int* __restrict__ ei, int* __restrict__ cnt) {
    int e = blockIdx.x * 256 + threadIdx.x;
    if (e < N_EDGES) atomicAdd(&cnt[ei[N_EDGES + e]], 1);
}

__global__ __launch_bounds__(1024) void scan1_kernel(const int* __restrict__ cnt,
                                                     int* __restrict__ exw,
                                                     int* __restrict__ bsum) {
    int b = blockIdx.x, t = threadIdx.x;
    int i = b * 1024 + t;
    int v = (i < N_NODES) ? cnt[i] : 0;
    int lane = t & 63, w = t >> 6;
    int s = v;
    #pragma unroll
    for (int off = 1; off < 64; off <<= 1) {
        int u = __shfl_up(s, off, 64);
        if (lane >= off) s += u;
    }
    __shared__ int ws[16];
    if (lane == 63) ws[w] = s;
    __syncthreads();
    if (t < 16) {
        int sv = ws[t];
        #pragma unroll
        for (int off = 1; off < 16; off <<= 1) {
            int u = __shfl_up(sv, off, 64);
            if (lane >= off) sv += u;
        }
        ws[t] = sv;
    }
    __syncthreads();
    int prefix = (w > 0) ? ws[w - 1] : 0;
    int incl = s + prefix;
    if (i < N_NODES) exw[i] = incl - v;
    if (t == 1023) bsum[b] = incl;
}

__global__ void scan2_kernel(int* __restrict__ bsum) {
    int t = threadIdx.x;
    int v = (t < SCAN_NB) ? bsum[t] : 0;
    #pragma unroll
    for (int off = 1; off < 64; off <<= 1) {
        int u = __shfl_up(v, off, 64);
        if (t >= off) v += u;
    }
    if (t < SCAN_NB) bsum[t] = v;
}

__global__ __launch_bounds__(1024) void scan3_kernel(const int* __restrict__ exw,
                                                     const int* __restrict__ bsum,
                                                     int* __restrict__ rp) {
    int b = blockIdx.x, t = threadIdx.x;
    int i = b * 1024 + t;
    if (i < N_NODES) rp[i] = exw[i] + (b > 0 ? bsum[b - 1] : 0);
    if (b == 0 && t == 0) rp[N_NODES] = bsum[SCAN_NB - 1];
}

__global__ void fill_kernel(const int* __restrict__ ei, const int* __restrict__ rp,
                            int* __restrict__ cur, int* __restrict__ el) {
    int e = blockIdx.x * 256 + threadIdx.x;
    if (e < N_EDGES) {
        int d = ei[N_EDGES + e];
        int p = atomicAdd(&cur[d], 1);
        el[rp[d] + p] = ei[e];
    }
}

// ---------------- weight prepacks (bf16, transposed for MFMA B-frags) ----------------
// WcT[l][j][c] (j=0..319 output col, c=0..63 K) <- Wc[c][j]
__global__ void repack_wct(const float* __restrict__ W1, const float* __restrict__ Wr,
                           unsigned short* __restrict__ WcT) {
    int t = blockIdx.x * 256 + threadIdx.x;
    if (t >= 3 * 320 * 64) return;
    int l = t / (320 * 64);
    int rem = t % (320 * 64);
    int j = rem / 64, c = rem % 64;
    float v;
    if (j < 128)      v = W1[(l * 128 + c) * 128 + j];
    else if (j < 256) v = W1[(l * 128 + 64 + c) * 128 + (j - 128)];
    else              v = Wr[(l * 64 + c) * 64 + (j - 256)];
    WcT[t] = f2bfu(v);
}

// W2T[l][n][k] (n=0..63 output col, k=0..127 K) <- W2[l][k][n]
__global__ void repack_w2t(const float* __restrict__ W2, unsigned short* __restrict__ W2T) {
    int t = blockIdx.x * 256 + threadIdx.x;
    if (t >= 3 * 64 * 128) return;
    int l = t / 8192, rem = t % 8192;
    int n = rem / 128, k = rem % 128;
    W2T[t] = f2bfu(W2[l * 8192 + k * 64 + n]);
}

// ---------------- encoder ----------------
__global__ __launch_bounds__(256) void encoder_kernel(
    const float* __restrict__ x, const float* __restrict__ W,
    const float* __restrict__ b, const float* __restrict__ g,
    const float* __restrict__ beta, float* __restrict__ out) {
    __shared__ float wlds[IN_CH * 64];
    for (int t = threadIdx.x; t < IN_CH * 64; t += 256) wlds[t] = W[t];
    __syncthreads();
    int lane = threadIdx.x & 63;
    int node = blockIdx.x * 4 + (threadIdx.x >> 6);
    if (node >= N_NODES) return;
    float xv = (lane < IN_CH) ? x[node * IN_CH + lane] : 0.f;
    float acc = b[lane];
    #pragma unroll
    for (int c = 0; c < IN_CH; ++c) {
        float xc = __shfl(xv, c, 64);
        acc += xc * wlds[c * 64 + lane];
    }
    float s = acc;
    for (int off = 32; off; off >>= 1) s += __shfl_xor(s, off, 64);
    float mu = s * (1.f / 64.f);
    float d = acc - mu;
    float q = d * d;
    for (int off = 32; off; off >>= 1) q += __shfl_xor(q, off, 64);
    float r = rsqrtf(q * (1.f / 64.f) + EPS);
    out[node * 64 + lane] = d * r * g[lane] + beta[lane];
}

// ---------------- MFMA fused kernel, 64-node tiles, 256 threads (4 waves)
// mode 0: [x -> LN+ReLU -> GEMM]            (first layer)
// mode 1: [x += S/deg@W2 + b2 + R -> LN+ReLU -> GEMM]
// mode 2: [x += S/deg@W2 + b2 + R]          (final update)
__global__ __launch_bounds__(256) void fused2_kernel(
    float* __restrict__ x, const unsigned int* __restrict__ S,
    const unsigned short* __restrict__ W2T, const float* __restrict__ b2,
    const int* __restrict__ rp, const float* __restrict__ g,
    const float* __restrict__ bvec, const unsigned short* __restrict__ WcT,
    const float* __restrict__ b1, float* __restrict__ A128,
    unsigned short* __restrict__ Bbf, float* __restrict__ R64, int mode) {
    __shared__ unsigned int sl[64 * 68];  // S tile (bf16x2); later h tile (stride 36)
    __shared__ float xl[64 * 68];         // x_new tile
    int tid = threadIdx.x;
    int lane = tid & 63, wid = tid >> 6;
    int l15 = lane & 15, g4 = lane >> 4;
    int r0 = wid * 16;
    int base = blockIdx.x * 64;
    int srow = tid >> 2, sq = tid & 3;  // staging/LN mapping: 4 threads per row

    if (mode != 0) {
        // stage S tile (coalesced)
        {
            int node = base + srow;
            #pragma unroll
            for (int i = 0; i < 4; ++i) {
                uint4 v = make_uint4(0, 0, 0, 0);
                if (node < N_NODES)
                    v = ((const uint4*)(S + (size_t)node * 64 + sq * 16))[i];
                *(uint4*)&sl[srow * 68 + sq * 16 + 4 * i] = v;
            }
        }
        __syncthreads();
        // S(64x128) @ W2(128x64): each wave does 16-row stripe
        bh8 sa[4];
        #pragma unroll
        for (int ks = 0; ks < 4; ++ks)
            sa[ks] = *(const bh8*)&sl[(r0 + l15) * 68 + ks * 16 + g4 * 4];
        fx4 acc[4];
        #pragma unroll
        for (int n = 0; n < 4; ++n) {
            acc[n] = (fx4){0.f, 0.f, 0.f, 0.f};
            #pragma unroll
            for (int ks = 0; ks < 4; ++ks) {
                bh8 bf = *(const bh8*)(W2T + ((n * 16 + l15) * 128 + ks * 32 + g4 * 8));
                acc[n] = __builtin_amdgcn_mfma_f32_16x16x32_bf16(sa[ks], bf, acc[n], 0, 0, 0);
            }
        }
        // epilogue: x += agg/deg + b2*msk + R
        float inv[4], msk[4];
        #pragma unroll
        for (int r = 0; r < 4; ++r) {
            int nd = base + r0 + g4 * 4 + r;
            int cv = (nd < N_NODES) ? (rp[nd + 1] - rp[nd]) : 0;
            inv[r] = cv > 0 ? 1.f / (float)cv : 0.f;
            msk[r] = cv > 0 ? 1.f : 0.f;
        }
        #pragma unroll
        for (int n = 0; n < 4; ++n) {
            int col = n * 16 + l15;
            float b2c = b2[col];
            #pragma unroll
            for (int r = 0; r < 4; ++r) {
                int row = r0 + g4 * 4 + r;
                int nd = base + row;
                float xn = 0.f;
                if (nd < N_NODES) {
                    float xo = x[(size_t)nd * 64 + col];
                    float ro = R64[(size_t)nd * 64 + col];
                    xn = xo + acc[n][r] * inv[r] + b2c * msk[r] + ro;
                    x[(size_t)nd * 64 + col] = xn;
                }
                if (mode == 1) xl[row * 68 + col] = xn;
            }
        }
        if (mode == 2) return;
        __syncthreads();
    }

    // ---- LN + ReLU: 4 threads per row, 16 cols each ----
    {
        float vv[16];
        if (mode == 0) {
            int node = base + srow;
            #pragma unroll
            for (int i = 0; i < 4; ++i) {
                float4 v = make_float4(0.f, 0.f, 0.f, 0.f);
                if (node < N_NODES)
                    v = ((const float4*)(x + (size_t)node * 64 + sq * 16))[i];
                vv[4 * i + 0] = v.x; vv[4 * i + 1] = v.y;
                vv[4 * i + 2] = v.z; vv[4 * i + 3] = v.w;
            }
        } else {
            #pragma unroll
            for (int i = 0; i < 16; ++i) vv[i] = xl[srow * 68 + sq * 16 + i];
        }
        float s = 0.f;
        #pragma unroll
        for (int i = 0; i < 16; ++i) s += vv[i];
        s += __shfl_xor(s, 1, 4);
        s += __shfl_xor(s, 2, 4);
        float mu = s * (1.f / 64.f);
        float q = 0.f;
        #pragma unroll
        for (int i = 0; i < 16; ++i) { float d = vv[i] - mu; q += d * d; }
        q += __shfl_xor(q, 1, 4);
        q += __shfl_xor(q, 2, 4);
        float rs = rsqrtf(q * (1.f / 64.f) + EPS);
        float gv[16], bv[16];
        #pragma unroll
        for (int i = 0; i < 4; ++i) {
            float4 gg = *(const float4*)&g[sq * 16 + 4 * i];
            float4 bb = *(const float4*)&bvec[sq * 16 + 4 * i];
            gv[4 * i] = gg.x; gv[4 * i + 1] = gg.y; gv[4 * i + 2] = gg.z; gv[4 * i + 3] = gg.w;
            bv[4 * i] = bb.x; bv[4 * i + 1] = bb.y; bv[4 * i + 2] = bb.z; bv[4 * i + 3] = bb.w;
        }
        // make sure all phase-1 reads of sl are done before overwriting (mode!=0)
        __syncthreads();
        #pragma unroll
        for (int j = 0; j < 8; ++j) {
            float h0 = fmaxf((vv[2 * j] - mu) * rs * gv[2 * j] + bv[2 * j], 0.f);
            float h1 = fmaxf((vv[2 * j + 1] - mu) * rs * gv[2 * j + 1] + bv[2 * j + 1], 0.f);
            sl[srow * 36 + sq * 8 + j] = f2bf(h0) | (f2bf(h1) << 16);
        }
    }
    __syncthreads();

    // ---- GEMM2: h(64x64) @ Wc(64x320), per-wave 16-row stripe ----
    bh8 a2[2];
    #pragma unroll
    for (int ks = 0; ks < 2; ++ks)
        a2[ks] = *(const bh8*)&sl[(r0 + l15) * 36 + ks * 16 + g4 * 4];
    #pragma unroll 4
    for (int n = 0; n < 20; ++n) {
        fx4 c = (fx4){0.f, 0.f, 0.f, 0.f};
        #pragma unroll
        for (int ks = 0; ks < 2; ++ks) {
            bh8 bf = *(const bh8*)(WcT + ((n * 16 + l15) * 64 + ks * 32 + g4 * 8));
            c = __builtin_amdgcn_mfma_f32_16x16x32_bf16(a2[ks], bf, c, 0, 0, 0);
        }
        int col = n * 16 + l15;
        #pragma unroll
        for (int r = 0; r < 4; ++r) {
            int nd = base + r0 + g4 * 4 + r;
            if (nd >= N_NODES) continue;
            float v = c[r];
            if (col < 128)       A128[(size_t)nd * 128 + col] = v + b1[col];
            else if (col < 256)  Bbf[(size_t)nd * 128 + (col - 128)] = f2bfu(v);
            else                 R64[(size_t)nd * 64 + (col - 256)] = v;
        }
    }
}

// ---------------- pure edge aggregation: S[i] = sum_src relu(A[i] + B[src]) (bf16 packed)
__global__ __launch_bounds__(256) void edge_agg_kernel(
    const float* __restrict__ A128, const unsigned int* __restrict__ B64,
    const int* __restrict__ rp, const int* __restrict__ el,
    unsigned int* __restrict__ S) {
    int lane = threadIdx.x & 63;
    int i = blockIdx.x * 4 + (threadIdx.x >> 6);
    if (i >= N_NODES) return;
    float2 a = ((const float2*)(A128 + (size_t)i * 128))[lane];
    int s0 = rp[i], s1 = rp[i + 1];
    float ax = 0.f, ay = 0.f;
    int e = s0;
    for (; e + 4 <= s1; e += 4) {
        int n0 = el[e], n1 = el[e + 1], n2 = el[e + 2], n3 = el[e + 3];
        unsigned int u0 = B64[(size_t)n0 * 64 + lane];
        unsigned int u1 = B64[(size_t)n1 * 64 + lane];
        unsigned int u2 = B64[(size_t)n2 * 64 + lane];
        unsigned int u3 = B64[(size_t)n3 * 64 + lane];
        ax += fmaxf(a.x + bflo(u0), 0.f) + fmaxf(a.x + bflo(u1), 0.f) +
              fmaxf(a.x + bflo(u2), 0.f) + fmaxf(a.x + bflo(u3), 0.f);
        ay += fmaxf(a.y + bfhi(u0), 0.f) + fmaxf(a.y + bfhi(u1), 0.f) +
              fmaxf(a.y + bfhi(u2), 0.f) + fmaxf(a.y + bfhi(u3), 0.f);
    }
    for (; e < s1; ++e) {
        int n = el[e];
        unsigned int u = B64[(size_t)n * 64 + lane];
        ax += fmaxf(a.x + bflo(u), 0.f);
        ay += fmaxf(a.y + bfhi(u), 0.f);
    }
    S[(size_t)i * 64 + lane] = f2bf(ax) | (f2bf(ay) << 16);
}

extern "C" void kernel_launch(void* const* d_in, const int* in_sizes, int n_in,
                              void* d_out, int out_size, void* d_ws, size_t ws_size,
                              hipStream_t stream) {
    const float* x       = (const float*)d_in[0];
    const int*   ei      = (const int*)d_in[1];
    const float* encW    = (const float*)d_in[2];
    const float* encb    = (const float*)d_in[3];
    const float* encg    = (const float*)d_in[4];
    const float* encbeta = (const float*)d_in[5];
    const float* lng     = (const float*)d_in[6];
    const float* lnb     = (const float*)d_in[7];
    const float* W1      = (const float*)d_in[8];
    const float* b1      = (const float*)d_in[9];
    const float* W2      = (const float*)d_in[10];
    const float* b2      = (const float*)d_in[11];
    const float* Wr      = (const float*)d_in[12];
    float* xout = (float*)d_out;

    char* ws = (char*)d_ws;
    size_t off = 0;
    auto alloc = [&](size_t bytes) -> void* {
        void* p = ws + off;
        off += (bytes + 255) & ~(size_t)255;
        return p;
    };
    unsigned short* WcT  = (unsigned short*)alloc(3 * 320 * 64 * sizeof(unsigned short));
    unsigned short* W2T  = (unsigned short*)alloc(3 * 64 * 128 * sizeof(unsigned short));
    float*          A128 = (float*)alloc((size_t)N_NODES * 128 * sizeof(float));
    unsigned short* Bbf  = (unsigned short*)alloc((size_t)N_NODES * 128 * sizeof(unsigned short));
    float*          R64  = (float*)alloc((size_t)N_NODES * 64 * sizeof(float));
    unsigned int*   Sbuf = (unsigned int*)alloc((size_t)N_NODES * 64 * sizeof(unsigned int));
    int*            cnt  = (int*)alloc(N_NODES * sizeof(int));
    int*            rp   = (int*)alloc((N_NODES + 1) * sizeof(int));
    int*            el   = (int*)alloc(N_EDGES * sizeof(int));
    int*            exw  = (int*)alloc(N_NODES * sizeof(int));
    int*            bsum = (int*)alloc(SCAN_NB * sizeof(int));

    hipMemsetAsync(cnt, 0, N_NODES * sizeof(int), stream);
    hist_kernel<<<(N_EDGES + 255) / 256, 256, 0, stream>>>(ei, cnt);
    scan1_kernel<<<SCAN_NB, 1024, 0, stream>>>(cnt, exw, bsum);
    scan2_kernel<<<1, 64, 0, stream>>>(bsum);
    scan3_kernel<<<SCAN_NB, 1024, 0, stream>>>(exw, bsum, rp);
    hipMemsetAsync(cnt, 0, N_NODES * sizeof(int), stream);
    fill_kernel<<<(N_EDGES + 255) / 256, 256, 0, stream>>>(ei, rp, cnt, el);
    repack_wct<<<(3 * 320 * 64 + 255) / 256, 256, 0, stream>>>(W1, Wr, WcT);
    repack_w2t<<<(3 * 64 * 128 + 255) / 256, 256, 0, stream>>>(W2, W2T);

    encoder_kernel<<<(N_NODES + 3) / 4, 256, 0, stream>>>(x, encW, encb, encg, encbeta, xout);

    int gblocks = (N_NODES + 63) / 64;
    for (int l = 0; l < 3; ++l) {
        const unsigned short* w2p = W2T + (size_t)(l > 0 ? l - 1 : 0) * 64 * 128;
        const float* b2p = b2 + (size_t)(l > 0 ? l - 1 : 0) * 64;
        fused2_kernel<<<gblocks, 256, 0, stream>>>(
            xout, Sbuf, w2p, b2p, rp, lng + l * 64, lnb + l * 64,
            WcT + (size_t)l * 320 * 64, b1 + l * 128, A128, Bbf, R64, l == 0 ? 0 : 1);
        edge_agg_kernel<<<(N_NODES + 3) / 4, 256, 0, stream>>>(
            A128, (const unsigned int*)Bbf, rp, el, Sbuf);
    }
    fused2_kernel<<<gblocks, 256, 0, stream>>>(
        xout, Sbuf, W2T + (size_t)2 * 64 * 128, b2 + 2 * 64, rp,
        lng, lnb, WcT, b1, A128, Bbf, R64, 2);
}

// Round 5
// 286.804 us; speedup vs baseline: 2.8900x; 1.0946x over previous
//
#include <hip/hip_runtime.h>
#include <hip/hip_bf16.h>

#define N_NODES 50000
#define N_EDGES 400000
#define IN_CH 32
#define EPS 1e-5f
#define SCAN_NB ((N_NODES + 1023) / 1024)

typedef __attribute__((ext_vector_type(8))) short bh8;
typedef __attribute__((ext_vector_type(4))) float fx4;

static __device__ __forceinline__ unsigned int f2bf(float f) {
    __hip_bfloat16 h = __float2bfloat16(f);
    return (unsigned int)*(unsigned short*)&h;
}
static __device__ __forceinline__ unsigned short f2bfu(float f) {
    __hip_bfloat16 h = __float2bfloat16(f);
    return *(unsigned short*)&h;
}
static __device__ __forceinline__ float bflo(unsigned int u) { return __uint_as_float(u << 16); }
static __device__ __forceinline__ float bfhi(unsigned int u) { return __uint_as_float(u & 0xffff0000u); }

// ---------------- CSR build ----------------
__global__ void hist_kernel(const int* __restrict__ ei, int* __restrict__ cnt) {
    int e = blockIdx.x * 256 + threadIdx.x;
    if (e < N_EDGES) atomicAdd(&cnt[ei[N_EDGES + e]], 1);
}

__global__ __launch_bounds__(1024) void scan1_kernel(const int* __restrict__ cnt,
                                                     int* __restrict__ exw,
                                                     int* __restrict__ bsum) {
    int b = blockIdx.x, t = threadIdx.x;
    int i = b * 1024 + t;
    int v = (i < N_NODES) ? cnt[i] : 0;
    int lane = t & 63, w = t >> 6;
    int s = v;
    #pragma unroll
    for (int off = 1; off < 64; off <<= 1) {
        int u = __shfl_up(s, off, 64);
        if (lane >= off) s += u;
    }
    __shared__ int ws[16];
    if (lane == 63) ws[w] = s;
    __syncthreads();
    if (t < 16) {
        int sv = ws[t];
        #pragma unroll
        for (int off = 1; off < 16; off <<= 1) {
            int u = __shfl_up(sv, off, 64);
            if (lane >= off) sv += u;
        }
        ws[t] = sv;
    }
    __syncthreads();
    int prefix = (w > 0) ? ws[w - 1] : 0;
    int incl = s + prefix;
    if (i < N_NODES) exw[i] = incl - v;
    if (t == 1023) bsum[b] = incl;
}

__global__ void scan2_kernel(int* __restrict__ bsum) {
    int t = threadIdx.x;
    int v = (t < SCAN_NB) ? bsum[t] : 0;
    #pragma unroll
    for (int off = 1; off < 64; off <<= 1) {
        int u = __shfl_up(v, off, 64);
        if (t >= off) v += u;
    }
    if (t < SCAN_NB) bsum[t] = v;
}

__global__ __launch_bounds__(1024) void scan3_kernel(const int* __restrict__ exw,
                                                     const int* __restrict__ bsum,
                                                     int* __restrict__ rp) {
    int b = blockIdx.x, t = threadIdx.x;
    int i = b * 1024 + t;
    if (i < N_NODES) rp[i] = exw[i] + (b > 0 ? bsum[b - 1] : 0);
    if (b == 0 && t == 0) rp[N_NODES] = bsum[SCAN_NB - 1];
}

__global__ void fill_kernel(const int* __restrict__ ei, const int* __restrict__ rp,
                            int* __restrict__ cur, int* __restrict__ el) {
    int e = blockIdx.x * 256 + threadIdx.x;
    if (e < N_EDGES) {
        int d = ei[N_EDGES + e];
        int p = atomicAdd(&cur[d], 1);
        el[rp[d] + p] = ei[e];
    }
}

// ---------------- weight prepacks (bf16, transposed for MFMA B-frags) ----------------
__global__ void repack_wct(const float* __restrict__ W1, const float* __restrict__ Wr,
                           unsigned short* __restrict__ WcT) {
    int t = blockIdx.x * 256 + threadIdx.x;
    if (t >= 3 * 320 * 64) return;
    int l = t / (320 * 64);
    int rem = t % (320 * 64);
    int j = rem / 64, c = rem % 64;
    float v;
    if (j < 128)      v = W1[(l * 128 + c) * 128 + j];
    else if (j < 256) v = W1[(l * 128 + 64 + c) * 128 + (j - 128)];
    else              v = Wr[(l * 64 + c) * 64 + (j - 256)];
    WcT[t] = f2bfu(v);
}

__global__ void repack_w2t(const float* __restrict__ W2, unsigned short* __restrict__ W2T) {
    int t = blockIdx.x * 256 + threadIdx.x;
    if (t >= 3 * 64 * 128) return;
    int l = t / 8192, rem = t % 8192;
    int n = rem / 128, k = rem % 128;
    W2T[t] = f2bfu(W2[l * 8192 + k * 64 + n]);
}

// ---------------- encoder ----------------
__global__ __launch_bounds__(256) void encoder_kernel(
    const float* __restrict__ x, const float* __restrict__ W,
    const float* __restrict__ b, const float* __restrict__ g,
    const float* __restrict__ beta, float* __restrict__ out) {
    __shared__ float wlds[IN_CH * 64];
    for (int t = threadIdx.x; t < IN_CH * 64; t += 256) wlds[t] = W[t];
    __syncthreads();
    int lane = threadIdx.x & 63;
    int node = blockIdx.x * 4 + (threadIdx.x >> 6);
    if (node >= N_NODES) return;
    float xv = (lane < IN_CH) ? x[node * IN_CH + lane] : 0.f;
    float acc = b[lane];
    #pragma unroll
    for (int c = 0; c < IN_CH; ++c) {
        float xc = __shfl(xv, c, 64);
        acc += xc * wlds[c * 64 + lane];
    }
    float s = acc;
    for (int off = 32; off; off >>= 1) s += __shfl_xor(s, off, 64);
    float mu = s * (1.f / 64.f);
    float d = acc - mu;
    float q = d * d;
    for (int off = 32; off; off >>= 1) q += __shfl_xor(q, off, 64);
    float r = rsqrtf(q * (1.f / 64.f) + EPS);
    out[node * 64 + lane] = d * r * g[lane] + beta[lane];
}

// ---------------- MFMA fused kernel: 32 nodes/block (2 stripes x 16), 256 thr (4 waves)
// wave pair (2s, 2s+1) owns stripe s; half=wid&1 splits output cols.
// mode 0: LN+ReLU -> GEMM ; mode 1: update -> LN+ReLU -> GEMM ; mode 2: update only
__global__ __launch_bounds__(256, 6) void fused3_kernel(
    float* __restrict__ x, const unsigned int* __restrict__ S,
    const unsigned short* __restrict__ W2T, const float* __restrict__ b2,
    const int* __restrict__ rp, const float* __restrict__ g,
    const float* __restrict__ bvec, const unsigned short* __restrict__ WcT,
    const float* __restrict__ b1, unsigned short* __restrict__ Abf,
    unsigned short* __restrict__ Bbf, float* __restrict__ R64, int mode) {
    __shared__ float bufF[2][1088];  // per-stripe: xf rows stride 68 ; then h rows stride 33 (uints)
    int tid = threadIdx.x;
    int lane = tid & 63, wid = tid >> 6;
    int l15 = lane & 15, g4 = lane >> 4;
    int stripe = wid >> 1, half = wid & 1;
    int base = blockIdx.x * 32;
    int row0 = base + stripe * 16;
    float* xf = &bufF[stripe][0];
    unsigned int* hU = (unsigned int*)&bufF[stripe][0];

    if (mode != 0) {
        int nd_l = row0 + g4 * 4;
        int cols[2];
        #pragma unroll
        for (int j = 0; j < 2; ++j) cols[j] = (half * 2 + j) * 16 + l15;
        // prefetch x, R64 (epilogue operands) and S fragments (direct from global, L2-hot)
        float xpre[2][4], rpre[2][4];
        #pragma unroll
        for (int j = 0; j < 2; ++j)
            #pragma unroll
            for (int r = 0; r < 4; ++r) {
                int nd = min(nd_l + r, N_NODES - 1);
                xpre[j][r] = x[(size_t)nd * 64 + cols[j]];
                rpre[j][r] = R64[(size_t)nd * 64 + cols[j]];
            }
        int srcrow = min(row0 + l15, N_NODES - 1);
        bh8 sa[4];
        #pragma unroll
        for (int ks = 0; ks < 4; ++ks)
            sa[ks] = *(const bh8*)(S + (size_t)srcrow * 64 + ks * 16 + g4 * 4);
        fx4 acc[2];
        #pragma unroll
        for (int j = 0; j < 2; ++j) {
            int n = half * 2 + j;
            acc[j] = (fx4){0.f, 0.f, 0.f, 0.f};
            #pragma unroll
            for (int ks = 0; ks < 4; ++ks) {
                bh8 bf = *(const bh8*)(W2T + ((size_t)(n * 16 + l15) * 128 + ks * 32 + g4 * 8));
                acc[j] = __builtin_amdgcn_mfma_f32_16x16x32_bf16(sa[ks], bf, acc[j], 0, 0, 0);
            }
        }
        float inv[4], msk[4];
        #pragma unroll
        for (int r = 0; r < 4; ++r) {
            int nd = nd_l + r;
            int cv = (nd < N_NODES) ? (rp[nd + 1] - rp[nd]) : 0;
            inv[r] = cv > 0 ? 1.f / (float)cv : 0.f;
            msk[r] = cv > 0 ? 1.f : 0.f;
        }
        #pragma unroll
        for (int j = 0; j < 2; ++j) {
            float b2c = b2[cols[j]];
            #pragma unroll
            for (int r = 0; r < 4; ++r) {
                int nd = nd_l + r;
                float xn = xpre[j][r] + acc[j][r] * inv[r] + b2c * msk[r] + rpre[j][r];
                if (nd < N_NODES) x[(size_t)nd * 64 + cols[j]] = xn;
                if (mode == 1) xf[(g4 * 4 + r) * 68 + cols[j]] = xn;
            }
        }
        if (mode == 2) return;
        __syncthreads();
    }

    // ---- LN + ReLU: 8 threads per row (32 rows), write h bf16x2 at stride 33 ----
    {
        int srow = tid >> 3, sq = tid & 7;
        int lstripe = srow >> 4, lr = srow & 15;
        float vv[8];
        if (mode == 0) {
            int nd = base + srow;
            float4 v0 = make_float4(0.f, 0.f, 0.f, 0.f), v1 = v0;
            if (nd < N_NODES) {
                v0 = ((const float4*)(x + (size_t)nd * 64 + sq * 8))[0];
                v1 = ((const float4*)(x + (size_t)nd * 64 + sq * 8))[1];
            }
            vv[0] = v0.x; vv[1] = v0.y; vv[2] = v0.z; vv[3] = v0.w;
            vv[4] = v1.x; vv[5] = v1.y; vv[6] = v1.z; vv[7] = v1.w;
        } else {
            #pragma unroll
            for (int i = 0; i < 8; ++i) vv[i] = bufF[lstripe][lr * 68 + sq * 8 + i];
        }
        float s = 0.f;
        #pragma unroll
        for (int i = 0; i < 8; ++i) s += vv[i];
        s += __shfl_xor(s, 1, 8);
        s += __shfl_xor(s, 2, 8);
        s += __shfl_xor(s, 4, 8);
        float mu = s * (1.f / 64.f);
        float q = 0.f;
        #pragma unroll
        for (int i = 0; i < 8; ++i) { float d = vv[i] - mu; q += d * d; }
        q += __shfl_xor(q, 1, 8);
        q += __shfl_xor(q, 2, 8);
        q += __shfl_xor(q, 4, 8);
        float rs = rsqrtf(q * (1.f / 64.f) + EPS);
        float4 g0 = *(const float4*)&g[sq * 8], g1 = *(const float4*)&g[sq * 8 + 4];
        float4 b0 = *(const float4*)&bvec[sq * 8], b1v = *(const float4*)&bvec[sq * 8 + 4];
        float gv[8] = {g0.x, g0.y, g0.z, g0.w, g1.x, g1.y, g1.z, g1.w};
        float bv[8] = {b0.x, b0.y, b0.z, b0.w, b1v.x, b1v.y, b1v.z, b1v.w};
        __syncthreads();  // all xf reads done before h overwrites the region
        unsigned int* hw = (unsigned int*)&bufF[lstripe][0];
        #pragma unroll
        for (int jj = 0; jj < 4; ++jj) {
            float h0 = fmaxf((vv[2 * jj] - mu) * rs * gv[2 * jj] + bv[2 * jj], 0.f);
            float h1 = fmaxf((vv[2 * jj + 1] - mu) * rs * gv[2 * jj + 1] + bv[2 * jj + 1], 0.f);
            hw[lr * 33 + sq * 4 + jj] = f2bf(h0) | (f2bf(h1) << 16);
        }
    }
    __syncthreads();

    // ---- GEMM2: h(16x64) @ Wc(64x320); wave does 10 of 20 col-blocks ----
    bh8 a2[2];
    #pragma unroll
    for (int ks = 0; ks < 2; ++ks)
        a2[ks] = *(const bh8*)&hU[l15 * 33 + ks * 16 + g4 * 4];
    int ndg = row0 + g4 * 4;
    #pragma unroll 2
    for (int nn = 0; nn < 10; ++nn) {
        int n = half * 10 + nn;
        fx4 c = (fx4){0.f, 0.f, 0.f, 0.f};
        #pragma unroll
        for (int ks = 0; ks < 2; ++ks) {
            bh8 bf = *(const bh8*)(WcT + ((size_t)(n * 16 + l15) * 64 + ks * 32 + g4 * 8));
            c = __builtin_amdgcn_mfma_f32_16x16x32_bf16(a2[ks], bf, c, 0, 0, 0);
        }
        int col = n * 16 + l15;
        #pragma unroll
        for (int r = 0; r < 4; ++r) {
            int nd = ndg + r;
            if (nd >= N_NODES) continue;
            float v = c[r];
            if (col < 128)       Abf[(size_t)nd * 128 + col] = f2bfu(v + b1[col]);
            else if (col < 256)  Bbf[(size_t)nd * 128 + (col - 128)] = f2bfu(v);
            else                 R64[(size_t)nd * 64 + (col - 256)] = v;
        }
    }
}

// ---------------- pure edge aggregation: S[i] = sum_src relu(A[i] + B[src]) (bf16 packed)
__global__ __launch_bounds__(256) void edge_agg_kernel(
    const unsigned int* __restrict__ A64, const unsigned int* __restrict__ B64,
    const int* __restrict__ rp, const int* __restrict__ el,
    unsigned int* __restrict__ S) {
    int lane = threadIdx.x & 63;
    int i = blockIdx.x * 4 + (threadIdx.x >> 6);
    if (i >= N_NODES) return;
    unsigned int av = A64[(size_t)i * 64 + lane];
    float axb = bflo(av), ayb = bfhi(av);
    int s0 = rp[i], s1 = rp[i + 1];
    float ax = 0.f, ay = 0.f;
    int e = s0;
    for (; e + 4 <= s1; e += 4) {
        int n0 = el[e], n1 = el[e + 1], n2 = el[e + 2], n3 = el[e + 3];
        unsigned int u0 = B64[(size_t)n0 * 64 + lane];
        unsigned int u1 = B64[(size_t)n1 * 64 + lane];
        unsigned int u2 = B64[(size_t)n2 * 64 + lane];
        unsigned int u3 = B64[(size_t)n3 * 64 + lane];
        ax += fmaxf(axb + bflo(u0), 0.f) + fmaxf(axb + bflo(u1), 0.f) +
              fmaxf(axb + bflo(u2), 0.f) + fmaxf(axb + bflo(u3), 0.f);
        ay += fmaxf(ayb + bfhi(u0), 0.f) + fmaxf(ayb + bfhi(u1), 0.f) +
              fmaxf(ayb + bfhi(u2), 0.f) + fmaxf(ayb + bfhi(u3), 0.f);
    }
    for (; e < s1; ++e) {
        int n = el[e];
        unsigned int u = B64[(size_t)n * 64 + lane];
        ax += fmaxf(axb + bflo(u), 0.f);
        ay += fmaxf(ayb + bfhi(u), 0.f);
    }
    S[(size_t)i * 64 + lane] = f2bf(ax) | (f2bf(ay) << 16);
}

extern "C" void kernel_launch(void* const* d_in, const int* in_sizes, int n_in,
                              void* d_out, int out_size, void* d_ws, size_t ws_size,
                              hipStream_t stream) {
    const float* x       = (const float*)d_in[0];
    const int*   ei      = (const int*)d_in[1];
    const float* encW    = (const float*)d_in[2];
    const float* encb    = (const float*)d_in[3];
    const float* encg    = (const float*)d_in[4];
    const float* encbeta = (const float*)d_in[5];
    const float* lng     = (const float*)d_in[6];
    const float* lnb     = (const float*)d_in[7];
    const float* W1      = (const float*)d_in[8];
    const float* b1      = (const float*)d_in[9];
    const float* W2      = (const float*)d_in[10];
    const float* b2      = (const float*)d_in[11];
    const float* Wr      = (const float*)d_in[12];
    float* xout = (float*)d_out;

    char* ws = (char*)d_ws;
    size_t off = 0;
    auto alloc = [&](size_t bytes) -> void* {
        void* p = ws + off;
        off += (bytes + 255) & ~(size_t)255;
        return p;
    };
    unsigned short* WcT  = (unsigned short*)alloc(3 * 320 * 64 * sizeof(unsigned short));
    unsigned short* W2T  = (unsigned short*)alloc(3 * 64 * 128 * sizeof(unsigned short));
    unsigned short* Abf  = (unsigned short*)alloc((size_t)N_NODES * 128 * sizeof(unsigned short));
    unsigned short* Bbf  = (unsigned short*)alloc((size_t)N_NODES * 128 * sizeof(unsigned short));
    float*          R64  = (float*)alloc((size_t)N_NODES * 64 * sizeof(float));
    unsigned int*   Sbuf = (unsigned int*)alloc((size_t)N_NODES * 64 * sizeof(unsigned int));
    int*            cnt  = (int*)alloc(N_NODES * sizeof(int));
    int*            rp   = (int*)alloc((N_NODES + 1) * sizeof(int));
    int*            el   = (int*)alloc(N_EDGES * sizeof(int));
    int*            exw  = (int*)alloc(N_NODES * sizeof(int));
    int*            bsum = (int*)alloc(SCAN_NB * sizeof(int));

    hipMemsetAsync(cnt, 0, N_NODES * sizeof(int), stream);
    hist_kernel<<<(N_EDGES + 255) / 256, 256, 0, stream>>>(ei, cnt);
    scan1_kernel<<<SCAN_NB, 1024, 0, stream>>>(cnt, exw, bsum);
    scan2_kernel<<<1, 64, 0, stream>>>(bsum);
    scan3_kernel<<<SCAN_NB, 1024, 0, stream>>>(exw, bsum, rp);
    hipMemsetAsync(cnt, 0, N_NODES * sizeof(int), stream);
    fill_kernel<<<(N_EDGES + 255) / 256, 256, 0, stream>>>(ei, rp, cnt, el);
    repack_wct<<<(3 * 320 * 64 + 255) / 256, 256, 0, stream>>>(W1, Wr, WcT);
    repack_w2t<<<(3 * 64 * 128 + 255) / 256, 256, 0, stream>>>(W2, W2T);

    encoder_kernel<<<(N_NODES + 3) / 4, 256, 0, stream>>>(x, encW, encb, encg, encbeta, xout);

    int gblocks = (N_NODES + 31) / 32;
    for (int l = 0; l < 3; ++l) {
        const unsigned short* w2p = W2T + (size_t)(l > 0 ? l - 1 : 0) * 64 * 128;
        const float* b2p = b2 + (size_t)(l > 0 ? l - 1 : 0) * 64;
        fused3_kernel<<<gblocks, 256, 0, stream>>>(
            xout, Sbuf, w2p, b2p, rp, lng + l * 64, lnb + l * 64,
            WcT + (size_t)l * 320 * 64, b1 + l * 128, Abf, Bbf, R64, l == 0 ? 0 : 1);
        edge_agg_kernel<<<(N_NODES + 3) / 4, 256, 0, stream>>>(
            (const unsigned int*)Abf, (const unsigned int*)Bbf, rp, el, Sbuf);
    }
    fused3_kernel<<<gblocks, 256, 0, stream>>>(
        xout, Sbuf, W2T + (size_t)2 * 64 * 128, b2 + 2 * 64, rp,
        lng, lnb, WcT, b1, Abf, Bbf, R64, 2);
}

// Round 6
// 272.235 us; speedup vs baseline: 3.0447x; 1.0535x over previous
//
#include <hip/hip_runtime.h>
#include <hip/hip_bf16.h>

#define N_NODES 50000
#define N_EDGES 400000
#define IN_CH 32
#define EPS 1e-5f
#define SCAN_NB ((N_NODES + 1023) / 1024)

typedef __attribute__((ext_vector_type(8))) short bh8;
typedef __attribute__((ext_vector_type(4))) float fx4;
typedef __attribute__((ext_vector_type(2))) float fx2;

static __device__ __forceinline__ unsigned int f2bf(float f) {
    __hip_bfloat16 h = __float2bfloat16(f);
    return (unsigned int)*(unsigned short*)&h;
}
static __device__ __forceinline__ unsigned short f2bfu(float f) {
    __hip_bfloat16 h = __float2bfloat16(f);
    return *(unsigned short*)&h;
}
static __device__ __forceinline__ float bflo(unsigned int u) { return __uint_as_float(u << 16); }
static __device__ __forceinline__ float bfhi(unsigned int u) { return __uint_as_float(u & 0xffff0000u); }

// ---------------- CSR build ----------------
__global__ void hist_kernel(const int* __restrict__ ei, int* __restrict__ cnt) {
    int e = blockIdx.x * 256 + threadIdx.x;
    if (e < N_EDGES) atomicAdd(&cnt[ei[N_EDGES + e]], 1);
}

__global__ __launch_bounds__(1024) void scan1_kernel(const int* __restrict__ cnt,
                                                     int* __restrict__ exw,
                                                     int* __restrict__ bsum) {
    int b = blockIdx.x, t = threadIdx.x;
    int i = b * 1024 + t;
    int v = (i < N_NODES) ? cnt[i] : 0;
    int lane = t & 63, w = t >> 6;
    int s = v;
    #pragma unroll
    for (int off = 1; off < 64; off <<= 1) {
        int u = __shfl_up(s, off, 64);
        if (lane >= off) s += u;
    }
    __shared__ int ws[16];
    if (lane == 63) ws[w] = s;
    __syncthreads();
    if (t < 16) {
        int sv = ws[t];
        #pragma unroll
        for (int off = 1; off < 16; off <<= 1) {
            int u = __shfl_up(sv, off, 64);
            if (lane >= off) sv += u;
        }
        ws[t] = sv;
    }
    __syncthreads();
    int prefix = (w > 0) ? ws[w - 1] : 0;
    int incl = s + prefix;
    if (i < N_NODES) exw[i] = incl - v;
    if (t == 1023) bsum[b] = incl;
}

// scan3: adds block-prefix (computed redundantly per block from bsum), zeroes cnt
__global__ __launch_bounds__(1024) void scan3_kernel(const int* __restrict__ exw,
                                                     const int* __restrict__ bsum,
                                                     int* __restrict__ rp,
                                                     int* __restrict__ cnt) {
    __shared__ int pfx;
    __shared__ int total;
    int b = blockIdx.x, t = threadIdx.x;
    if (t < 64) {
        int v = (t < SCAN_NB) ? bsum[t] : 0;
        #pragma unroll
        for (int off = 1; off < 64; off <<= 1) {
            int u = __shfl_up(v, off, 64);
            if (t >= off) v += u;
        }
        if (b == 0 && t == 0) pfx = 0;
        if (b > 0 && t == b - 1) pfx = v;
        if (t == SCAN_NB - 1) total = v;
    }
    __syncthreads();
    int i = b * 1024 + t;
    if (i < N_NODES) {
        rp[i] = exw[i] + pfx;
        cnt[i] = 0;
    }
    if (b == 0 && t == 0) rp[N_NODES] = total;
}

__global__ void fill_kernel(const int* __restrict__ ei, const int* __restrict__ rp,
                            int* __restrict__ cur, int* __restrict__ el) {
    int e = blockIdx.x * 256 + threadIdx.x;
    if (e < N_EDGES) {
        int d = ei[N_EDGES + e];
        int p = atomicAdd(&cur[d], 1);
        el[rp[d] + p] = ei[e];
    }
}

// ---------------- merged weight prepacks (bf16, transposed for MFMA B-frags) ----------------
// part 1: WcT[l][j][c] <- {W1 top | W1 bot | Wr}   part 2: W2T[l][n][k] <- W2[l][k][n]
#define WCT_TOT (3 * 320 * 64)
#define W2T_TOT (3 * 64 * 128)
__global__ void repack_kernel(const float* __restrict__ W1, const float* __restrict__ Wr,
                              const float* __restrict__ W2,
                              unsigned short* __restrict__ WcT,
                              unsigned short* __restrict__ W2T) {
    int t = blockIdx.x * 256 + threadIdx.x;
    if (t < WCT_TOT) {
        int l = t / (320 * 64);
        int rem = t % (320 * 64);
        int j = rem / 64, c = rem % 64;
        float v;
        if (j < 128)      v = W1[(l * 128 + c) * 128 + j];
        else if (j < 256) v = W1[(l * 128 + 64 + c) * 128 + (j - 128)];
        else              v = Wr[(l * 64 + c) * 64 + (j - 256)];
        WcT[t] = f2bfu(v);
    } else if (t < WCT_TOT + W2T_TOT) {
        int t2 = t - WCT_TOT;
        int l = t2 / 8192, rem = t2 % 8192;
        int n = rem / 128, k = rem % 128;
        W2T[t2] = f2bfu(W2[l * 8192 + k * 64 + n]);
    }
}

// ---------------- encoder ----------------
__global__ __launch_bounds__(256) void encoder_kernel(
    const float* __restrict__ x, const float* __restrict__ W,
    const float* __restrict__ b, const float* __restrict__ g,
    const float* __restrict__ beta, float* __restrict__ out) {
    __shared__ float wlds[IN_CH * 64];
    for (int t = threadIdx.x; t < IN_CH * 64; t += 256) wlds[t] = W[t];
    __syncthreads();
    int lane = threadIdx.x & 63;
    int node = blockIdx.x * 4 + (threadIdx.x >> 6);
    if (node >= N_NODES) return;
    float xv = (lane < IN_CH) ? x[node * IN_CH + lane] : 0.f;
    float acc = b[lane];
    #pragma unroll
    for (int c = 0; c < IN_CH; ++c) {
        float xc = __shfl(xv, c, 64);
        acc += xc * wlds[c * 64 + lane];
    }
    float s = acc;
    for (int off = 32; off; off >>= 1) s += __shfl_xor(s, off, 64);
    float mu = s * (1.f / 64.f);
    float d = acc - mu;
    float q = d * d;
    for (int off = 32; off; off >>= 1) q += __shfl_xor(q, off, 64);
    float r = rsqrtf(q * (1.f / 64.f) + EPS);
    out[node * 64 + lane] = d * r * g[lane] + beta[lane];
}

// ---------------- MFMA fused kernel: 32 nodes/block (2 stripes x 16), 256 thr (4 waves)
// mode 0: LN+ReLU -> GEMM ; mode 1: update -> LN+ReLU -> GEMM ; mode 2: update only
__global__ __launch_bounds__(256, 6) void fused3_kernel(
    float* __restrict__ x, const unsigned int* __restrict__ S,
    const unsigned short* __restrict__ W2T, const float* __restrict__ b2,
    const int* __restrict__ rp, const float* __restrict__ g,
    const float* __restrict__ bvec, const unsigned short* __restrict__ WcT,
    const float* __restrict__ b1, unsigned short* __restrict__ Abf,
    unsigned char* __restrict__ Bf8, float* __restrict__ R64, int mode) {
    __shared__ float bufF[2][1088];  // per-stripe: xf rows stride 68 ; then h rows stride 33 (uints)
    int tid = threadIdx.x;
    int lane = tid & 63, wid = tid >> 6;
    int l15 = lane & 15, g4 = lane >> 4;
    int stripe = wid >> 1, half = wid & 1;
    int base = blockIdx.x * 32;
    int row0 = base + stripe * 16;
    float* xf = &bufF[stripe][0];
    unsigned int* hU = (unsigned int*)&bufF[stripe][0];

    if (mode != 0) {
        int nd_l = row0 + g4 * 4;
        int cols[2];
        #pragma unroll
        for (int j = 0; j < 2; ++j) cols[j] = (half * 2 + j) * 16 + l15;
        float xpre[2][4], rpre[2][4];
        #pragma unroll
        for (int j = 0; j < 2; ++j)
            #pragma unroll
            for (int r = 0; r < 4; ++r) {
                int nd = min(nd_l + r, N_NODES - 1);
                xpre[j][r] = x[(size_t)nd * 64 + cols[j]];
                rpre[j][r] = R64[(size_t)nd * 64 + cols[j]];
            }
        int srcrow = min(row0 + l15, N_NODES - 1);
        bh8 sa[4];
        #pragma unroll
        for (int ks = 0; ks < 4; ++ks)
            sa[ks] = *(const bh8*)(S + (size_t)srcrow * 64 + ks * 16 + g4 * 4);
        fx4 acc[2];
        #pragma unroll
        for (int j = 0; j < 2; ++j) {
            int n = half * 2 + j;
            acc[j] = (fx4){0.f, 0.f, 0.f, 0.f};
            #pragma unroll
            for (int ks = 0; ks < 4; ++ks) {
                bh8 bf = *(const bh8*)(W2T + ((size_t)(n * 16 + l15) * 128 + ks * 32 + g4 * 8));
                acc[j] = __builtin_amdgcn_mfma_f32_16x16x32_bf16(sa[ks], bf, acc[j], 0, 0, 0);
            }
        }
        float inv[4], msk[4];
        #pragma unroll
        for (int r = 0; r < 4; ++r) {
            int nd = nd_l + r;
            int cv = (nd < N_NODES) ? (rp[nd + 1] - rp[nd]) : 0;
            inv[r] = cv > 0 ? 1.f / (float)cv : 0.f;
            msk[r] = cv > 0 ? 1.f : 0.f;
        }
        #pragma unroll
        for (int j = 0; j < 2; ++j) {
            float b2c = b2[cols[j]];
            #pragma unroll
            for (int r = 0; r < 4; ++r) {
                int nd = nd_l + r;
                float xn = xpre[j][r] + acc[j][r] * inv[r] + b2c * msk[r] + rpre[j][r];
                if (nd < N_NODES) x[(size_t)nd * 64 + cols[j]] = xn;
                if (mode == 1) xf[(g4 * 4 + r) * 68 + cols[j]] = xn;
            }
        }
        if (mode == 2) return;
        __syncthreads();
    }

    // ---- LN + ReLU: 8 threads per row (32 rows), write h bf16x2 at stride 33 ----
    {
        int srow = tid >> 3, sq = tid & 7;
        int lstripe = srow >> 4, lr = srow & 15;
        float vv[8];
        if (mode == 0) {
            int nd = base + srow;
            float4 v0 = make_float4(0.f, 0.f, 0.f, 0.f), v1 = v0;
            if (nd < N_NODES) {
                v0 = ((const float4*)(x + (size_t)nd * 64 + sq * 8))[0];
                v1 = ((const float4*)(x + (size_t)nd * 64 + sq * 8))[1];
            }
            vv[0] = v0.x; vv[1] = v0.y; vv[2] = v0.z; vv[3] = v0.w;
            vv[4] = v1.x; vv[5] = v1.y; vv[6] = v1.z; vv[7] = v1.w;
        } else {
            #pragma unroll
            for (int i = 0; i < 8; ++i) vv[i] = bufF[lstripe][lr * 68 + sq * 8 + i];
        }
        float s = 0.f;
        #pragma unroll
        for (int i = 0; i < 8; ++i) s += vv[i];
        s += __shfl_xor(s, 1, 8);
        s += __shfl_xor(s, 2, 8);
        s += __shfl_xor(s, 4, 8);
        float mu = s * (1.f / 64.f);
        float q = 0.f;
        #pragma unroll
        for (int i = 0; i < 8; ++i) { float d = vv[i] - mu; q += d * d; }
        q += __shfl_xor(q, 1, 8);
        q += __shfl_xor(q, 2, 8);
        q += __shfl_xor(q, 4, 8);
        float rs = rsqrtf(q * (1.f / 64.f) + EPS);
        float4 g0 = *(const float4*)&g[sq * 8], g1 = *(const float4*)&g[sq * 8 + 4];
        float4 b0 = *(const float4*)&bvec[sq * 8], b1v = *(const float4*)&bvec[sq * 8 + 4];
        float gv[8] = {g0.x, g0.y, g0.z, g0.w, g1.x, g1.y, g1.z, g1.w};
        float bv[8] = {b0.x, b0.y, b0.z, b0.w, b1v.x, b1v.y, b1v.z, b1v.w};
        __syncthreads();
        unsigned int* hw = (unsigned int*)&bufF[lstripe][0];
        #pragma unroll
        for (int jj = 0; jj < 4; ++jj) {
            float h0 = fmaxf((vv[2 * jj] - mu) * rs * gv[2 * jj] + bv[2 * jj], 0.f);
            float h1 = fmaxf((vv[2 * jj + 1] - mu) * rs * gv[2 * jj + 1] + bv[2 * jj + 1], 0.f);
            hw[lr * 33 + sq * 4 + jj] = f2bf(h0) | (f2bf(h1) << 16);
        }
    }
    __syncthreads();

    // ---- GEMM2: h(16x64) @ Wc(64x320); wave does 10 of 20 col-blocks ----
    bh8 a2[2];
    #pragma unroll
    for (int ks = 0; ks < 2; ++ks)
        a2[ks] = *(const bh8*)&hU[l15 * 33 + ks * 16 + g4 * 4];
    int ndg = row0 + g4 * 4;
    #pragma unroll 2
    for (int nn = 0; nn < 10; ++nn) {
        int n = half * 10 + nn;
        fx4 c = (fx4){0.f, 0.f, 0.f, 0.f};
        #pragma unroll
        for (int ks = 0; ks < 2; ++ks) {
            bh8 bf = *(const bh8*)(WcT + ((size_t)(n * 16 + l15) * 64 + ks * 32 + g4 * 8));
            c = __builtin_amdgcn_mfma_f32_16x16x32_bf16(a2[ks], bf, c, 0, 0, 0);
        }
        int col = n * 16 + l15;
        #pragma unroll
        for (int r = 0; r < 4; ++r) {
            int nd = ndg + r;
            if (nd >= N_NODES) continue;
            float v = c[r];
            if (col < 128) {
                Abf[(size_t)nd * 128 + col] = f2bfu(v + b1[col]);
            } else if (col < 256) {
                unsigned int p = __builtin_amdgcn_cvt_pk_fp8_f32(v, v, 0, false);
                Bf8[(size_t)nd * 128 + (col - 128)] = (unsigned char)(p & 0xFF);
            } else {
                R64[(size_t)nd * 64 + (col - 256)] = v;
            }
        }
    }
}

// ---------------- pure edge aggregation: S[i] = sum_src relu(A[i] + B[src]) ----------------
// A: bf16 pairs; B: fp8 e4m3 (2 per lane); 8-deep index prefetch for MLP
__global__ __launch_bounds__(256, 8) void edge_agg_kernel(
    const unsigned int* __restrict__ A64, const unsigned short* __restrict__ B8,
    const int* __restrict__ rp, const int* __restrict__ el,
    unsigned int* __restrict__ S) {
    int lane = threadIdx.x & 63;
    int i = blockIdx.x * 4 + (threadIdx.x >> 6);
    if (i >= N_NODES) return;
    unsigned int av = A64[(size_t)i * 64 + lane];
    float axb = bflo(av), ayb = bfhi(av);
    int s0 = rp[i], s1 = rp[i + 1];
    float ax = 0.f, ay = 0.f;
    int e = s0;
    for (; e + 8 <= s1; e += 8) {
        int n[8];
        #pragma unroll
        for (int j = 0; j < 8; ++j) n[j] = el[e + j];
        unsigned short u[8];
        #pragma unroll
        for (int j = 0; j < 8; ++j) u[j] = B8[(size_t)n[j] * 64 + lane];
        #pragma unroll
        for (int j = 0; j < 8; ++j) {
            fx2 f = __builtin_amdgcn_cvt_pk_f32_fp8((int)u[j], false);
            ax += fmaxf(axb + f.x, 0.f);
            ay += fmaxf(ayb + f.y, 0.f);
        }
    }
    if (e + 4 <= s1) {
        int n[4];
        #pragma unroll
        for (int j = 0; j < 4; ++j) n[j] = el[e + j];
        unsigned short u[4];
        #pragma unroll
        for (int j = 0; j < 4; ++j) u[j] = B8[(size_t)n[j] * 64 + lane];
        #pragma unroll
        for (int j = 0; j < 4; ++j) {
            fx2 f = __builtin_amdgcn_cvt_pk_f32_fp8((int)u[j], false);
            ax += fmaxf(axb + f.x, 0.f);
            ay += fmaxf(ayb + f.y, 0.f);
        }
        e += 4;
    }
    for (; e < s1; ++e) {
        int n = el[e];
        unsigned short u = B8[(size_t)n * 64 + lane];
        fx2 f = __builtin_amdgcn_cvt_pk_f32_fp8((int)u, false);
        ax += fmaxf(axb + f.x, 0.f);
        ay += fmaxf(ayb + f.y, 0.f);
    }
    S[(size_t)i * 64 + lane] = f2bf(ax) | (f2bf(ay) << 16);
}

extern "C" void kernel_launch(void* const* d_in, const int* in_sizes, int n_in,
                              void* d_out, int out_size, void* d_ws, size_t ws_size,
                              hipStream_t stream) {
    const float* x       = (const float*)d_in[0];
    const int*   ei      = (const int*)d_in[1];
    const float* encW    = (const float*)d_in[2];
    const float* encb    = (const float*)d_in[3];
    const float* encg    = (const float*)d_in[4];
    const float* encbeta = (const float*)d_in[5];
    const float* lng     = (const float*)d_in[6];
    const float* lnb     = (const float*)d_in[7];
    const float* W1      = (const float*)d_in[8];
    const float* b1      = (const float*)d_in[9];
    const float* W2      = (const float*)d_in[10];
    const float* b2      = (const float*)d_in[11];
    const float* Wr      = (const float*)d_in[12];
    float* xout = (float*)d_out;

    char* ws = (char*)d_ws;
    size_t off = 0;
    auto alloc = [&](size_t bytes) -> void* {
        void* p = ws + off;
        off += (bytes + 255) & ~(size_t)255;
        return p;
    };
    unsigned short* WcT  = (unsigned short*)alloc(3 * 320 * 64 * sizeof(unsigned short));
    unsigned short* W2T  = (unsigned short*)alloc(3 * 64 * 128 * sizeof(unsigned short));
    unsigned short* Abf  = (unsigned short*)alloc((size_t)N_NODES * 128 * sizeof(unsigned short));
    unsigned char*  Bf8  = (unsigned char*)alloc((size_t)N_NODES * 128 * sizeof(unsigned char));
    float*          R64  = (float*)alloc((size_t)N_NODES * 64 * sizeof(float));
    unsigned int*   Sbuf = (unsigned int*)alloc((size_t)N_NODES * 64 * sizeof(unsigned int));
    int*            cnt  = (int*)alloc(N_NODES * sizeof(int));
    int*            rp   = (int*)alloc((N_NODES + 1) * sizeof(int));
    int*            el   = (int*)alloc(N_EDGES * sizeof(int));
    int*            exw  = (int*)alloc(N_NODES * sizeof(int));
    int*            bsum = (int*)alloc(SCAN_NB * sizeof(int));

    hipMemsetAsync(cnt, 0, N_NODES * sizeof(int), stream);
    hist_kernel<<<(N_EDGES + 255) / 256, 256, 0, stream>>>(ei, cnt);
    scan1_kernel<<<SCAN_NB, 1024, 0, stream>>>(cnt, exw, bsum);
    scan3_kernel<<<SCAN_NB, 1024, 0, stream>>>(exw, bsum, rp, cnt);
    fill_kernel<<<(N_EDGES + 255) / 256, 256, 0, stream>>>(ei, rp, cnt, el);
    repack_kernel<<<(WCT_TOT + W2T_TOT + 255) / 256, 256, 0, stream>>>(W1, Wr, W2, WcT, W2T);

    encoder_kernel<<<(N_NODES + 3) / 4, 256, 0, stream>>>(x, encW, encb, encg, encbeta, xout);

    int gblocks = (N_NODES + 31) / 32;
    for (int l = 0; l < 3; ++l) {
        const unsigned short* w2p = W2T + (size_t)(l > 0 ? l - 1 : 0) * 64 * 128;
        const float* b2p = b2 + (size_t)(l > 0 ? l - 1 : 0) * 64;
        fused3_kernel<<<gblocks, 256, 0, stream>>>(
            xout, Sbuf, w2p, b2p, rp, lng + l * 64, lnb + l * 64,
            WcT + (size_t)l * 320 * 64, b1 + l * 128, Abf, Bf8, R64, l == 0 ? 0 : 1);
        edge_agg_kernel<<<(N_NODES + 3) / 4, 256, 0, stream>>>(
            (const unsigned int*)Abf, (const unsigned short*)Bf8, rp, el, Sbuf);
    }
    fused3_kernel<<<gblocks, 256, 0, stream>>>(
        xout, Sbuf, W2T + (size_t)2 * 64 * 128, b2 + 2 * 64, rp,
        lng, lnb, WcT, b1, Abf, Bf8, R64, 2);
}

// Round 7
// 244.877 us; speedup vs baseline: 3.3849x; 1.1117x over previous
//
#include <hip/hip_runtime.h>
#include <hip/hip_bf16.h>

#define N_NODES 50000
#define N_EDGES 400000
#define IN_CH 32
#define EPS 1e-5f
#define SCAN_NB ((N_NODES + 1023) / 1024)
#define EL_CAP 1024

typedef __attribute__((ext_vector_type(8))) short bh8;
typedef __attribute__((ext_vector_type(4))) float fx4;
typedef __attribute__((ext_vector_type(2))) float fx2;

static __device__ __forceinline__ unsigned int f2bf(float f) {
    __hip_bfloat16 h = __float2bfloat16(f);
    return (unsigned int)*(unsigned short*)&h;
}
static __device__ __forceinline__ unsigned short f2bfu(float f) {
    __hip_bfloat16 h = __float2bfloat16(f);
    return *(unsigned short*)&h;
}
static __device__ __forceinline__ float bflo(unsigned int u) { return __uint_as_float(u << 16); }
static __device__ __forceinline__ float bfhi(unsigned int u) { return __uint_as_float(u & 0xffff0000u); }

// ---------------- CSR build ----------------
__global__ void hist_kernel(const int* __restrict__ ei, int* __restrict__ cnt) {
    int e = blockIdx.x * 256 + threadIdx.x;
    if (e < N_EDGES) atomicAdd(&cnt[ei[N_EDGES + e]], 1);
}

__global__ __launch_bounds__(1024) void scan1_kernel(const int* __restrict__ cnt,
                                                     int* __restrict__ exw,
                                                     int* __restrict__ bsum) {
    int b = blockIdx.x, t = threadIdx.x;
    int i = b * 1024 + t;
    int v = (i < N_NODES) ? cnt[i] : 0;
    int lane = t & 63, w = t >> 6;
    int s = v;
    #pragma unroll
    for (int off = 1; off < 64; off <<= 1) {
        int u = __shfl_up(s, off, 64);
        if (lane >= off) s += u;
    }
    __shared__ int ws[16];
    if (lane == 63) ws[w] = s;
    __syncthreads();
    if (t < 16) {
        int sv = ws[t];
        #pragma unroll
        for (int off = 1; off < 16; off <<= 1) {
            int u = __shfl_up(sv, off, 64);
            if (lane >= off) sv += u;
        }
        ws[t] = sv;
    }
    __syncthreads();
    int prefix = (w > 0) ? ws[w - 1] : 0;
    int incl = s + prefix;
    if (i < N_NODES) exw[i] = incl - v;
    if (t == 1023) bsum[b] = incl;
}

__global__ __launch_bounds__(1024) void scan3_kernel(const int* __restrict__ exw,
                                                     const int* __restrict__ bsum,
                                                     int* __restrict__ rp,
                                                     int* __restrict__ cnt) {
    __shared__ int pfx;
    __shared__ int total;
    int b = blockIdx.x, t = threadIdx.x;
    if (t < 64) {
        int v = (t < SCAN_NB) ? bsum[t] : 0;
        #pragma unroll
        for (int off = 1; off < 64; off <<= 1) {
            int u = __shfl_up(v, off, 64);
            if (t >= off) v += u;
        }
        if (b == 0 && t == 0) pfx = 0;
        if (b > 0 && t == b - 1) pfx = v;
        if (t == SCAN_NB - 1) total = v;
    }
    __syncthreads();
    int i = b * 1024 + t;
    if (i < N_NODES) {
        rp[i] = exw[i] + pfx;
        cnt[i] = 0;
    }
    if (b == 0 && t == 0) rp[N_NODES] = total;
}

__global__ void fill_kernel(const int* __restrict__ ei, const int* __restrict__ rp,
                            int* __restrict__ cur, int* __restrict__ el) {
    int e = blockIdx.x * 256 + threadIdx.x;
    if (e < N_EDGES) {
        int d = ei[N_EDGES + e];
        int p = atomicAdd(&cur[d], 1);
        el[rp[d] + p] = ei[e];
    }
}

// ---------------- merged weight prepacks ----------------
#define WCT_TOT (3 * 320 * 64)
#define W2T_TOT (3 * 64 * 128)
__global__ void repack_kernel(const float* __restrict__ W1, const float* __restrict__ Wr,
                              const float* __restrict__ W2,
                              unsigned short* __restrict__ WcT,
                              unsigned short* __restrict__ W2T) {
    int t = blockIdx.x * 256 + threadIdx.x;
    if (t < WCT_TOT) {
        int l = t / (320 * 64);
        int rem = t % (320 * 64);
        int j = rem / 64, c = rem % 64;
        float v;
        if (j < 128)      v = W1[(l * 128 + c) * 128 + j];
        else if (j < 256) v = W1[(l * 128 + 64 + c) * 128 + (j - 128)];
        else              v = Wr[(l * 64 + c) * 64 + (j - 256)];
        WcT[t] = f2bfu(v);
    } else if (t < WCT_TOT + W2T_TOT) {
        int t2 = t - WCT_TOT;
        int l = t2 / 8192, rem = t2 % 8192;
        int n = rem / 128, k = rem % 128;
        W2T[t2] = f2bfu(W2[l * 8192 + k * 64 + n]);
    }
}

// ---------------- encoder ----------------
__global__ __launch_bounds__(256) void encoder_kernel(
    const float* __restrict__ x, const float* __restrict__ W,
    const float* __restrict__ b, const float* __restrict__ g,
    const float* __restrict__ beta, float* __restrict__ out) {
    __shared__ float wlds[IN_CH * 64];
    for (int t = threadIdx.x; t < IN_CH * 64; t += 256) wlds[t] = W[t];
    __syncthreads();
    int lane = threadIdx.x & 63;
    int node = blockIdx.x * 4 + (threadIdx.x >> 6);
    if (node >= N_NODES) return;
    float xv = (lane < IN_CH) ? x[node * IN_CH + lane] : 0.f;
    float acc = b[lane];
    #pragma unroll
    for (int c = 0; c < IN_CH; ++c) {
        float xc = __shfl(xv, c, 64);
        acc += xc * wlds[c * 64 + lane];
    }
    float s = acc;
    for (int off = 32; off; off >>= 1) s += __shfl_xor(s, off, 64);
    float mu = s * (1.f / 64.f);
    float d = acc - mu;
    float q = d * d;
    for (int off = 32; off; off >>= 1) q += __shfl_xor(q, off, 64);
    float r = rsqrtf(q * (1.f / 64.f) + EPS);
    out[node * 64 + lane] = d * r * g[lane] + beta[lane];
}

// ---------------- fused4: [gather S (own 32 nodes) -> update] -> LN+ReLU -> GEMM
// mode 0: LN+GEMM only (first layer). mode 1: full. mode 2: gather+update only (final).
// A/B gather inputs are the PREVIOUS layer's outputs (ping-pong buffers).
__global__ __launch_bounds__(256, 4) void fused4_kernel(
    float* __restrict__ x,
    const unsigned short* __restrict__ AbfI, const unsigned char* __restrict__ B8I,
    const unsigned short* __restrict__ W2T, const float* __restrict__ b2,
    const int* __restrict__ rp, const int* __restrict__ el,
    const float* __restrict__ g, const float* __restrict__ bvec,
    const unsigned short* __restrict__ WcT, const float* __restrict__ b1,
    unsigned short* __restrict__ AbfO, unsigned char* __restrict__ B8O,
    unsigned short* __restrict__ Rbf, int mode) {
    __shared__ float bufF[2][1088];        // per-stripe: xf stride 68 ; then h stride 33 (uints)
    __shared__ unsigned int slds[32][68];  // gathered S tile, bf16 pairs (row-major, 64 pairs + pad)
    __shared__ int el_lds[EL_CAP];
    __shared__ int rp_lds[33];
    int tid = threadIdx.x;
    int lane = tid & 63, wid = tid >> 6;
    int l15 = lane & 15, g4 = lane >> 4;
    int stripe = wid >> 1, half = wid & 1;
    int base = blockIdx.x * 32;
    int row0 = base + stripe * 16;
    float* xf = &bufF[stripe][0];
    unsigned int* hU = (unsigned int*)&bufF[stripe][0];
    int n = tid >> 3, sq = tid & 7;  // gather/LN mapping: 8 threads per row

    if (mode != 0) {
        if (tid < 33) rp_lds[tid] = rp[min(base + tid, N_NODES)];
        __syncthreads();
        int e0 = rp_lds[0];
        int nE = rp_lds[32] - e0;
        bool inl = (nE <= EL_CAP);
        if (inl) for (int t = tid; t < nE; t += 256) el_lds[t] = el[e0 + t];

        // early-issue update-phase operands (hide under gather)
        int nd_l = row0 + g4 * 4;
        int cols[2];
        #pragma unroll
        for (int j = 0; j < 2; ++j) cols[j] = (half * 2 + j) * 16 + l15;
        float xpre[2][4], rpre[2][4];
        #pragma unroll
        for (int j = 0; j < 2; ++j)
            #pragma unroll
            for (int r = 0; r < 4; ++r) {
                int nd = min(nd_l + r, N_NODES - 1);
                xpre[j][r] = x[(size_t)nd * 64 + cols[j]];
                rpre[j][r] = bflo((unsigned int)Rbf[(size_t)nd * 64 + cols[j]]);
            }

        // own-node A row (16 cols per thread)
        int nd_g = base + n;
        float av[16], acc[16];
        #pragma unroll
        for (int i = 0; i < 16; ++i) { av[i] = 0.f; acc[i] = 0.f; }
        if (nd_g < N_NODES) {
            uint4 a0 = *(const uint4*)(AbfI + (size_t)nd_g * 128 + sq * 16);
            uint4 a1 = *(const uint4*)(AbfI + (size_t)nd_g * 128 + sq * 16 + 8);
            unsigned int aw[8] = {a0.x, a0.y, a0.z, a0.w, a1.x, a1.y, a1.z, a1.w};
            #pragma unroll
            for (int q = 0; q < 8; ++q) { av[2 * q] = bflo(aw[q]); av[2 * q + 1] = bfhi(aw[q]); }
        }
        __syncthreads();  // el_lds ready

        int es = rp_lds[n] - e0, ee = rp_lds[n + 1] - e0;
        int e2 = es;
        for (; e2 + 2 <= ee; e2 += 2) {
            int s0 = inl ? el_lds[e2] : el[e0 + e2];
            int s1 = inl ? el_lds[e2 + 1] : el[e0 + e2 + 1];
            uint4 b0 = *(const uint4*)(B8I + (size_t)s0 * 128 + sq * 16);
            uint4 b1w = *(const uint4*)(B8I + (size_t)s1 * 128 + sq * 16);
            unsigned int w0[4] = {b0.x, b0.y, b0.z, b0.w};
            unsigned int w1[4] = {b1w.x, b1w.y, b1w.z, b1w.w};
            #pragma unroll
            for (int q = 0; q < 4; ++q) {
                fx2 f0 = __builtin_amdgcn_cvt_pk_f32_fp8((int)w0[q], false);
                fx2 f1 = __builtin_amdgcn_cvt_pk_f32_fp8((int)w0[q], true);
                acc[4 * q + 0] += fmaxf(av[4 * q + 0] + f0.x, 0.f);
                acc[4 * q + 1] += fmaxf(av[4 * q + 1] + f0.y, 0.f);
                acc[4 * q + 2] += fmaxf(av[4 * q + 2] + f1.x, 0.f);
                acc[4 * q + 3] += fmaxf(av[4 * q + 3] + f1.y, 0.f);
            }
            #pragma unroll
            for (int q = 0; q < 4; ++q) {
                fx2 f0 = __builtin_amdgcn_cvt_pk_f32_fp8((int)w1[q], false);
                fx2 f1 = __builtin_amdgcn_cvt_pk_f32_fp8((int)w1[q], true);
                acc[4 * q + 0] += fmaxf(av[4 * q + 0] + f0.x, 0.f);
                acc[4 * q + 1] += fmaxf(av[4 * q + 1] + f0.y, 0.f);
                acc[4 * q + 2] += fmaxf(av[4 * q + 2] + f1.x, 0.f);
                acc[4 * q + 3] += fmaxf(av[4 * q + 3] + f1.y, 0.f);
            }
        }
        if (e2 < ee) {
            int s0 = inl ? el_lds[e2] : el[e0 + e2];
            uint4 b0 = *(const uint4*)(B8I + (size_t)s0 * 128 + sq * 16);
            unsigned int w0[4] = {b0.x, b0.y, b0.z, b0.w};
            #pragma unroll
            for (int q = 0; q < 4; ++q) {
                fx2 f0 = __builtin_amdgcn_cvt_pk_f32_fp8((int)w0[q], false);
                fx2 f1 = __builtin_amdgcn_cvt_pk_f32_fp8((int)w0[q], true);
                acc[4 * q + 0] += fmaxf(av[4 * q + 0] + f0.x, 0.f);
                acc[4 * q + 1] += fmaxf(av[4 * q + 1] + f0.y, 0.f);
                acc[4 * q + 2] += fmaxf(av[4 * q + 2] + f1.x, 0.f);
                acc[4 * q + 3] += fmaxf(av[4 * q + 3] + f1.y, 0.f);
            }
        }
        #pragma unroll
        for (int j = 0; j < 8; ++j)
            slds[n][sq * 8 + j] = f2bf(acc[2 * j]) | (f2bf(acc[2 * j + 1]) << 16);
        __syncthreads();

        // ---- S(16x128) @ W2T -> update x ----
        bh8 sa[4];
        #pragma unroll
        for (int ks = 0; ks < 4; ++ks)
            sa[ks] = *(const bh8*)&slds[stripe * 16 + l15][ks * 16 + g4 * 4];
        fx4 accm[2];
        #pragma unroll
        for (int j = 0; j < 2; ++j) {
            int nb = half * 2 + j;
            accm[j] = (fx4){0.f, 0.f, 0.f, 0.f};
            #pragma unroll
            for (int ks = 0; ks < 4; ++ks) {
                bh8 bf = *(const bh8*)(W2T + ((size_t)(nb * 16 + l15) * 128 + ks * 32 + g4 * 8));
                accm[j] = __builtin_amdgcn_mfma_f32_16x16x32_bf16(sa[ks], bf, accm[j], 0, 0, 0);
            }
        }
        float inv[4], msk[4];
        #pragma unroll
        for (int r = 0; r < 4; ++r) {
            int lcl = stripe * 16 + g4 * 4 + r;
            int cv = rp_lds[lcl + 1] - rp_lds[lcl];
            inv[r] = cv > 0 ? 1.f / (float)cv : 0.f;
            msk[r] = cv > 0 ? 1.f : 0.f;
        }
        #pragma unroll
        for (int j = 0; j < 2; ++j) {
            float b2c = b2[cols[j]];
            #pragma unroll
            for (int r = 0; r < 4; ++r) {
                int nd = nd_l + r;
                float xn = xpre[j][r] + accm[j][r] * inv[r] + b2c * msk[r] + rpre[j][r];
                if (nd < N_NODES) x[(size_t)nd * 64 + cols[j]] = xn;
                if (mode == 1) xf[(g4 * 4 + r) * 68 + cols[j]] = xn;
            }
        }
        if (mode == 2) return;
        __syncthreads();
    }

    // ---- LN + ReLU: 8 threads per row, write h bf16x2 at stride 33 ----
    {
        int lstripe = n >> 4, lr = n & 15;
        float vv[8];
        if (mode == 0) {
            int nd = base + n;
            float4 v0 = make_float4(0.f, 0.f, 0.f, 0.f), v1 = v0;
            if (nd < N_NODES) {
                v0 = ((const float4*)(x + (size_t)nd * 64 + sq * 8))[0];
                v1 = ((const float4*)(x + (size_t)nd * 64 + sq * 8))[1];
            }
            vv[0] = v0.x; vv[1] = v0.y; vv[2] = v0.z; vv[3] = v0.w;
            vv[4] = v1.x; vv[5] = v1.y; vv[6] = v1.z; vv[7] = v1.w;
        } else {
            #pragma unroll
            for (int i = 0; i < 8; ++i) vv[i] = bufF[lstripe][lr * 68 + sq * 8 + i];
        }
        float s = 0.f;
        #pragma unroll
        for (int i = 0; i < 8; ++i) s += vv[i];
        s += __shfl_xor(s, 1, 8);
        s += __shfl_xor(s, 2, 8);
        s += __shfl_xor(s, 4, 8);
        float mu = s * (1.f / 64.f);
        float q = 0.f;
        #pragma unroll
        for (int i = 0; i < 8; ++i) { float d = vv[i] - mu; q += d * d; }
        q += __shfl_xor(q, 1, 8);
        q += __shfl_xor(q, 2, 8);
        q += __shfl_xor(q, 4, 8);
        float rs = rsqrtf(q * (1.f / 64.f) + EPS);
        float4 g0 = *(const float4*)&g[sq * 8], g1 = *(const float4*)&g[sq * 8 + 4];
        float4 b0 = *(const float4*)&bvec[sq * 8], b1v = *(const float4*)&bvec[sq * 8 + 4];
        float gv[8] = {g0.x, g0.y, g0.z, g0.w, g1.x, g1.y, g1.z, g1.w};
        float bv[8] = {b0.x, b0.y, b0.z, b0.w, b1v.x, b1v.y, b1v.z, b1v.w};
        __syncthreads();
        unsigned int* hw = (unsigned int*)&bufF[lstripe][0];
        #pragma unroll
        for (int jj = 0; jj < 4; ++jj) {
            float h0 = fmaxf((vv[2 * jj] - mu) * rs * gv[2 * jj] + bv[2 * jj], 0.f);
            float h1 = fmaxf((vv[2 * jj + 1] - mu) * rs * gv[2 * jj + 1] + bv[2 * jj + 1], 0.f);
            hw[lr * 33 + sq * 4 + jj] = f2bf(h0) | (f2bf(h1) << 16);
        }
    }
    __syncthreads();

    // ---- GEMM2: h(16x64) @ Wc(64x320); wave does 10 of 20 col-blocks ----
    bh8 a2[2];
    #pragma unroll
    for (int ks = 0; ks < 2; ++ks)
        a2[ks] = *(const bh8*)&hU[l15 * 33 + ks * 16 + g4 * 4];
    int ndg = row0 + g4 * 4;
    #pragma unroll 2
    for (int nn = 0; nn < 10; ++nn) {
        int nb = half * 10 + nn;
        fx4 c = (fx4){0.f, 0.f, 0.f, 0.f};
        #pragma unroll
        for (int ks = 0; ks < 2; ++ks) {
            bh8 bf = *(const bh8*)(WcT + ((size_t)(nb * 16 + l15) * 64 + ks * 32 + g4 * 8));
            c = __builtin_amdgcn_mfma_f32_16x16x32_bf16(a2[ks], bf, c, 0, 0, 0);
        }
        int col = nb * 16 + l15;
        #pragma unroll
        for (int r = 0; r < 4; ++r) {
            int nd = ndg + r;
            if (nd >= N_NODES) continue;
            float v = c[r];
            if (col < 128) {
                AbfO[(size_t)nd * 128 + col] = f2bfu(v + b1[col]);
            } else if (col < 256) {
                unsigned int p = __builtin_amdgcn_cvt_pk_fp8_f32(v, v, 0, false);
                B8O[(size_t)nd * 128 + (col - 128)] = (unsigned char)(p & 0xFF);
            } else {
                Rbf[(size_t)nd * 64 + (col - 256)] = f2bfu(v);
            }
        }
    }
}

extern "C" void kernel_launch(void* const* d_in, const int* in_sizes, int n_in,
                              void* d_out, int out_size, void* d_ws, size_t ws_size,
                              hipStream_t stream) {
    const float* x       = (const float*)d_in[0];
    const int*   ei      = (const int*)d_in[1];
    const float* encW    = (const float*)d_in[2];
    const float* encb    = (const float*)d_in[3];
    const float* encg    = (const float*)d_in[4];
    const float* encbeta = (const float*)d_in[5];
    const float* lng     = (const float*)d_in[6];
    const float* lnb     = (const float*)d_in[7];
    const float* W1      = (const float*)d_in[8];
    const float* b1      = (const float*)d_in[9];
    const float* W2      = (const float*)d_in[10];
    const float* b2      = (const float*)d_in[11];
    const float* Wr      = (const float*)d_in[12];
    float* xout = (float*)d_out;

    char* ws = (char*)d_ws;
    size_t off = 0;
    auto alloc = [&](size_t bytes) -> void* {
        void* p = ws + off;
        off += (bytes + 255) & ~(size_t)255;
        return p;
    };
    unsigned short* WcT  = (unsigned short*)alloc(3 * 320 * 64 * sizeof(unsigned short));
    unsigned short* W2T  = (unsigned short*)alloc(3 * 64 * 128 * sizeof(unsigned short));
    unsigned short* Abf0 = (unsigned short*)alloc((size_t)N_NODES * 128 * sizeof(unsigned short));
    unsigned short* Abf1 = (unsigned short*)alloc((size_t)N_NODES * 128 * sizeof(unsigned short));
    unsigned char*  B80  = (unsigned char*)alloc((size_t)N_NODES * 128);
    unsigned char*  B81  = (unsigned char*)alloc((size_t)N_NODES * 128);
    unsigned short* Rbf  = (unsigned short*)alloc((size_t)N_NODES * 64 * sizeof(unsigned short));
    int*            cnt  = (int*)alloc(N_NODES * sizeof(int));
    int*            rp   = (int*)alloc((N_NODES + 1) * sizeof(int));
    int*            el   = (int*)alloc(N_EDGES * sizeof(int));
    int*            exw  = (int*)alloc(N_NODES * sizeof(int));
    int*            bsum = (int*)alloc(SCAN_NB * sizeof(int));

    hipMemsetAsync(cnt, 0, N_NODES * sizeof(int), stream);
    hist_kernel<<<(N_EDGES + 255) / 256, 256, 0, stream>>>(ei, cnt);
    scan1_kernel<<<SCAN_NB, 1024, 0, stream>>>(cnt, exw, bsum);
    scan3_kernel<<<SCAN_NB, 1024, 0, stream>>>(exw, bsum, rp, cnt);
    fill_kernel<<<(N_EDGES + 255) / 256, 256, 0, stream>>>(ei, rp, cnt, el);
    repack_kernel<<<(WCT_TOT + W2T_TOT + 255) / 256, 256, 0, stream>>>(W1, Wr, W2, WcT, W2T);

    encoder_kernel<<<(N_NODES + 3) / 4, 256, 0, stream>>>(x, encW, encb, encg, encbeta, xout);

    int gblocks = (N_NODES + 31) / 32;
    // layer 0: LN+GEMM only, writes pair0
    fused4_kernel<<<gblocks, 256, 0, stream>>>(
        xout, Abf0, B80, W2T, b2, rp, el, lng, lnb,
        WcT, b1, Abf0, B80, Rbf, 0);
    // layer 1: gather pair0 (layer0 W2), writes pair1
    fused4_kernel<<<gblocks, 256, 0, stream>>>(
        xout, Abf0, B80, W2T, b2, rp, el, lng + 64, lnb + 64,
        WcT + (size_t)1 * 320 * 64, b1 + 128, Abf1, B81, Rbf, 1);
    // layer 2: gather pair1 (layer1 W2), writes pair0
    fused4_kernel<<<gblocks, 256, 0, stream>>>(
        xout, Abf1, B81, W2T + (size_t)1 * 64 * 128, b2 + 64, rp, el, lng + 128, lnb + 128,
        WcT + (size_t)2 * 320 * 64, b1 + 256, Abf0, B80, Rbf, 1);
    // final: gather pair0 (layer2 W2), update only
    fused4_kernel<<<gblocks, 256, 0, stream>>>(
        xout, Abf0, B80, W2T + (size_t)2 * 64 * 128, b2 + 128, rp, el, lng, lnb,
        WcT, b1, Abf1, B81, Rbf, 2);
}